// Round 9
// baseline (897.382 us; speedup 1.0000x reference)
//
#include <hip/hip_runtime.h>
#include <math.h>

#define EPS 1e-4f
#define DEGB 128      // blocks in range-partitioned CSR build
#define DRANGE 512    // nodes per block: DEGB*DRANGE = 65536 >= N

__device__ __forceinline__ float sigmoidf_(float x){ return 1.0f/(1.0f+expf(-x)); }

// ---- ordered-uint mapping for float atomic min/max ----
__device__ __forceinline__ unsigned f2u_(float f){
    unsigned u = __float_as_uint(f);
    return (u & 0x80000000u) ? ~u : (u | 0x80000000u);
}
__device__ __forceinline__ float u2f_(unsigned u){
    unsigned b = (u & 0x80000000u) ? (u & 0x7FFFFFFFu) : ~u;
    return __uint_as_float(b);
}

// ================= init: all memsets in one launch =================
__global__ void init_kernel(unsigned* __restrict__ mm,
                            int* __restrict__ vhead, int V,
                            float* __restrict__ pz, int PZ){
    int i = blockIdx.x*blockDim.x + threadIdx.x;
    int stride = gridDim.x*blockDim.x;
    if (i == 0){ mm[0] = 0xFFFFFFFFu; mm[1] = 0u; }
    for (int t = i; t < V; t += stride) vhead[t] = -1;
    for (int t = i; t < PZ; t += stride) pz[t] = 0.f;
}

// ================= deg histogram, node-range partitioned (NO global atomics) ==========
// R8 evidence: prep_kernel's 800K device-scope atomicAdds = 28MB memory-side sector
// traffic at ~0.7TB/s = 44us (VALUBusy 0.7%). Each block owns a 512-node range,
// re-reads all dsts (L2-resident, 128x3.2MB @ 34.5TB/s ~ 12us) and counts into a
// 2KB LDS histogram; deg written coalesced. Minmax fused (independent output).
__global__ __launch_bounds__(1024)
void deg_hist(const float* __restrict__ pos, int n3, unsigned* mm,
              const int* __restrict__ ei, int* __restrict__ deg, int E, int N){
    __shared__ int cnt[DRANGE];
    __shared__ float slo[16], shi[16];
    for (int t = threadIdx.x; t < DRANGE; t += blockDim.x) cnt[t] = 0;

    // minmax over this block's slice of pos
    int per = (n3 + gridDim.x - 1)/gridDim.x;
    int p0 = blockIdx.x*per, p1 = min(n3, p0+per);
    float lo = INFINITY, hi = -INFINITY;
    for (int i = p0 + (int)threadIdx.x; i < p1; i += blockDim.x){
        float v = pos[i]; lo = fminf(lo, v); hi = fmaxf(hi, v);
    }
    for (int o = 32; o > 0; o >>= 1){
        lo = fminf(lo, __shfl_down(lo, o));
        hi = fmaxf(hi, __shfl_down(hi, o));
    }
    int wid = threadIdx.x >> 6;
    if ((threadIdx.x & 63) == 0){ slo[wid] = lo; shi[wid] = hi; }
    __syncthreads();                       // covers cnt zeroing too
    if (threadIdx.x == 0){
        for (int w = 1; w < 16; w++){ lo = fminf(lo, slo[w]); hi = fmaxf(hi, shi[w]); }
        atomicMin(&mm[0], f2u_(lo));
        atomicMax(&mm[1], f2u_(hi));
    }

    // LDS histogram of my node range
    int base = blockIdx.x * DRANGE;
    const int* dst = ei + E;
    for (int e = threadIdx.x; e < E; e += blockDim.x){
        int d = dst[e] - base;
        if ((unsigned)d < DRANGE) atomicAdd(&cnt[d], 1);
    }
    __syncthreads();
    for (int t = threadIdx.x; t < DRANGE; t += blockDim.x){
        int n = base + t;
        if (n < N) deg[n] = cnt[t];
    }
}

// ================= CSR scan (3-kernel parallel, proven in R3) =================
__global__ __launch_bounds__(256)
void scan_bsum(const int* __restrict__ deg, int* __restrict__ bsum, int N){
    int i = blockIdx.x*256 + threadIdx.x;
    int v = (i < N) ? deg[i] : 0;
    for (int o = 32; o > 0; o >>= 1) v += __shfl_down(v, o);
    __shared__ int ws[4];
    if ((threadIdx.x & 63) == 0) ws[threadIdx.x >> 6] = v;
    __syncthreads();
    if (threadIdx.x == 0) bsum[blockIdx.x] = ws[0] + ws[1] + ws[2] + ws[3];
}

__global__ __launch_bounds__(1024)
void scan_top(int* __restrict__ bsum, int NB){
    __shared__ int sh[1024];
    int t = threadIdx.x;
    int v = (t < NB) ? bsum[t] : 0;
    sh[t] = v;
    __syncthreads();
    for (int d = 1; d < 1024; d <<= 1){
        int u = (t >= d) ? sh[t - d] : 0;
        __syncthreads();
        sh[t] += u;
        __syncthreads();
    }
    if (t < NB) bsum[t] = sh[t] - v;
    if (t == 1023) bsum[NB] = sh[1023];
}

__global__ __launch_bounds__(256)
void scan_final(const int* __restrict__ deg, const int* __restrict__ bsum,
                int* __restrict__ off, int N, int NB){
    __shared__ int sh[256];
    int b = blockIdx.x;
    int i = b*256 + threadIdx.x;
    int v = (i < N) ? deg[i] : 0;
    sh[threadIdx.x] = v;
    __syncthreads();
    for (int d = 1; d < 256; d <<= 1){
        int u = (threadIdx.x >= d) ? sh[threadIdx.x - d] : 0;
        __syncthreads();
        sh[threadIdx.x] += u;
        __syncthreads();
    }
    if (i < N) off[i] = bsum[b] + sh[threadIdx.x] - v;    // exclusive
    if (b == 0 && threadIdx.x == 0) off[N] = bsum[NB];
}

// ====== pack, node-range partitioned: LDS rank + COALESCED record scatter ======
// A block's nodes occupy a contiguous ~125KB slot window -> every 32B sector in the
// window is fully written (L2-resident), killing the random-scatter sector tax of the
// old edge_pack. Within-node order is LDS-atomic order (any order valid: sum only).
__global__ __launch_bounds__(1024)
void edge_pack2(const int* __restrict__ ei, const float* __restrict__ pseudo,
                const float* __restrict__ x, const int* __restrict__ eoff,
                float4* __restrict__ rec4, int* __restrict__ recb, int E, int N){
    __shared__ int cnt[DRANGE];
    for (int t = threadIdx.x; t < DRANGE; t += blockDim.x) cnt[t] = 0;
    __syncthreads();
    int base = blockIdx.x * DRANGE;
    const int* dst = ei + E;
    for (int e = threadIdx.x; e < E; e += blockDim.x){
        int d = dst[e];
        int dl = d - base;
        if ((unsigned)dl < DRANGE){
            int r = atomicAdd(&cnt[dl], 1);
            int slot = eoff[d] + r;
            float p0 = pseudo[3*e], p1 = pseudo[3*e+1], p2 = pseudo[3*e+2];
            int s = ei[e];
            float v0 = p0*4.f, v1 = p1*4.f, v2 = p2*4.f;
            float f0 = fminf(fmaxf(floorf(v0), 0.f), 3.f);
            float f1 = fminf(fmaxf(floorf(v1), 0.f), 3.f);
            float f2 = fminf(fmaxf(floorf(v2), 0.f), 3.f);
            rec4[slot] = make_float4(v0 - f0, v1 - f1, v2 - f2, x[s]);
            recb[slot] = ((int)f0*5 + (int)f1)*5 + (int)f2;
        }
    }
}

__device__ __forceinline__ int voxel_id(const float* __restrict__ pos, int n, int G,
                                        float start, float size){
    int g[3];
    #pragma unroll
    for (int k = 0; k < 3; k++){
        float gg = floorf((pos[(size_t)n*3 + k] - start) / size);
        gg = fminf(fmaxf(gg, 0.f), (float)(G - 1));
        g[k] = (int)gg;
    }
    return (g[0]*G + g[1])*G + g[2];
}

__device__ __forceinline__ void pool_geom(const unsigned* mm, int G, int mode,
                                          float& start, float& size){
    float mn = u2f_(mm[0]), mx = u2f_(mm[1]);
    if (mode == 0){ start = mn; size = (mx + 0.001f - mn) / (float)G; }
    else          { start = mn - 0.5f; size = mx - mn + 1.0f; }
}

// ===== fused spline gather + node finalize: 8 lanes per node (tid = n*8+k) =====
__global__ __launch_bounds__(256)
void spline_node_kernel(const float* __restrict__ x, const float4* __restrict__ rec4,
                        const int* __restrict__ recb, const int* __restrict__ off,
                        const float* __restrict__ W,
                        const float* __restrict__ root, const float* __restrict__ bias,
                        const float* __restrict__ lin_w, const float* __restrict__ lin_b,
                        float* __restrict__ pose, float* __restrict__ act, int N){
    __shared__ float Ws[125*17];
    for (int i = threadIdx.x; i < 125*16; i += blockDim.x)
        Ws[(i >> 4)*17 + (i & 15)] = W[i];
    __syncthreads();
    int t = blockIdx.x*blockDim.x + threadIdx.x;
    int n = t >> 3;
    int k = t & 7;
    if (n >= N) return;     // group-uniform guard (all 8 lanes share n)

    int o0 = off[n], o1 = off[n+1];

    float agg[16];
    #pragma unroll
    for (int o = 0; o < 16; o++) agg[o] = 0.f;

    for (int s = o0 + k; s < o1; s += 8){
        float4 rv = rec4[s];
        int base = recb[s];
        float fr0 = rv.x, fr1 = rv.y, fr2 = rv.z, xv = rv.w;
        #pragma unroll
        for (int b = 0; b < 8; b++){
            int b0 = (b >> 2) & 1, b1 = (b >> 1) & 1, b2 = b & 1;
            float w = (b0 ? fr0 : 1.f - fr0) * (b1 ? fr1 : 1.f - fr1) * (b2 ? fr2 : 1.f - fr2);
            w *= xv;
            const float* Wr = &Ws[(base + b0*25 + b1*5 + b2)*17];
            #pragma unroll
            for (int o = 0; o < 16; o++) agg[o] += w * Wr[o];
        }
    }

    #pragma unroll
    for (int o = 0; o < 16; o++){
        agg[o] += __shfl_xor(agg[o], 1);
        agg[o] += __shfl_xor(agg[o], 2);
        agg[o] += __shfl_xor(agg[o], 4);
    }

    if (k != 0) return;

    float deg = fmaxf((float)(o1 - o0), 1.0f);
    float xs = x[n];
    float qv0 = lin_b[0], qv1 = lin_b[1], qv2 = lin_b[2], qv3 = lin_b[3];
    #pragma unroll
    for (int o = 0; o < 16; o++){
        float h = agg[o] / deg + xs * root[o] + bias[o];
        float e = (h > 0.f) ? h : expm1f(h);
        qv0 += e * lin_w[o*4 + 0];
        qv1 += e * lin_w[o*4 + 1];
        qv2 += e * lin_w[o*4 + 2];
        qv3 += e * lin_w[o*4 + 3];
    }
    float inv = 1.0f / (sqrtf(qv0*qv0 + qv1*qv1 + qv2*qv2 + qv3*qv3) + EPS);
    pose[(size_t)n*4 + 0] = qv0*inv;
    pose[(size_t)n*4 + 1] = qv1*inv;
    pose[(size_t)n*4 + 2] = qv2*inv;
    pose[(size_t)n*4 + 3] = qv3*inv;
    act[n] = xs;
}

// ====== wave-level routing core (R6-verified math, 8-lane group) ======
__device__ __forceinline__ void quat_pred(const float* qq, float px, float py, float pz,
                                          float pw, float* pr){
    float qx=qq[0], qy=qq[1], qz=qq[2], qw=qq[3];
    float tx = qw*px + qx*pw + qy*pz - qz*py;
    float ty = qw*py - qx*pz + qy*pw + qz*px;
    float tz = qw*pz + qx*py - qy*px + qz*pw;
    float tw = qw*pw - qx*px - qy*py - qz*pz;
    float inv = 1.f/(sqrtf(tx*tx+ty*ty+tz*tz+tw*tw)+EPS);
    pr[0]=tx*inv; pr[1]=ty*inv; pr[2]=tz*inv; pr[3]=tw*inv;
}

template<int I>
__device__ __forceinline__ void caps_route8(const float (*pr)[4], const float* a, bool on,
                                            float* c, float& v0, float& v1,
                                            float& v2, float& v3){
    float b[I];
    #pragma unroll
    for (int i = 0; i < I; i++) b[i] = on ? 0.f : -INFINITY;
    v0=v1=v2=v3=0.f;
    #pragma unroll
    for (int t = 0; t < 3; t++){
        #pragma unroll
        for (int i = 0; i < I; i++){
            float mb = b[i];
            mb = fmaxf(mb, __shfl_xor(mb, 1));
            mb = fmaxf(mb, __shfl_xor(mb, 2));
            mb = fmaxf(mb, __shfl_xor(mb, 4));
            float e = on ? expf(b[i] - mb) : 0.f;
            float s = e;
            s += __shfl_xor(s, 1);
            s += __shfl_xor(s, 2);
            s += __shfl_xor(s, 4);
            c[i] = a[i] * e / s;
        }
        float s0=0.f, s1=0.f, s2=0.f, s3=0.f;
        #pragma unroll
        for (int i = 0; i < I; i++){
            s0 += c[i]*pr[i][0]; s1 += c[i]*pr[i][1];
            s2 += c[i]*pr[i][2]; s3 += c[i]*pr[i][3];
        }
        float inv = 1.f/(sqrtf(s0*s0+s1*s1+s2*s2+s3*s3)+EPS);
        v0=s0*inv; v1=s1*inv; v2=s2*inv; v3=s3*inv;
        if (t < 2){
            #pragma unroll
            for (int i = 0; i < I; i++)
                b[i] += pr[i][0]*v0 + pr[i][1]*v1 + pr[i][2]*v2 + pr[i][3]*v3;
        }
    }
}

// ====== caps<1,6> + caps<6,6> + pool1 elist build, fused per node ======
__global__ __launch_bounds__(256)
void caps01_kernel(const float* __restrict__ pose0, const float* __restrict__ act0,
                   const float* __restrict__ q0, const float* __restrict__ q1,
                   float* __restrict__ poseOut, float* __restrict__ actOut,
                   const float* __restrict__ pos, int* __restrict__ vhead,
                   int* __restrict__ vnxt, int N, int G,
                   const unsigned* __restrict__ mm){
    __shared__ float qn0[6*4], qn1[36*4];
    for (int t = threadIdx.x; t < 6; t += blockDim.x){
        float qa=q0[t*4],qb=q0[t*4+1],qc=q0[t*4+2],qd=q0[t*4+3];
        float inv=1.f/(sqrtf(qa*qa+qb*qb+qc*qc+qd*qd)+EPS);
        qn0[t*4]=qa*inv; qn0[t*4+1]=qb*inv; qn0[t*4+2]=qc*inv; qn0[t*4+3]=qd*inv;
    }
    for (int t = threadIdx.x; t < 36; t += blockDim.x){
        float qa=q1[t*4],qb=q1[t*4+1],qc=q1[t*4+2],qd=q1[t*4+3];
        float inv=1.f/(sqrtf(qa*qa+qb*qb+qc*qc+qd*qd)+EPS);
        qn1[t*4]=qa*inv; qn1[t*4+1]=qb*inv; qn1[t*4+2]=qc*inv; qn1[t*4+3]=qd*inv;
    }
    __syncthreads();
    int tid = blockIdx.x*blockDim.x + threadIdx.x;
    int n = tid >> 3, j = tid & 7;
    if (n >= N) return;          // group-uniform
    bool on = (j < 6);

    // layer 0 (I=1, J=6)
    float4 p0 = *reinterpret_cast<const float4*>(&pose0[(size_t)n*4]);
    float aa0[1] = { act0[n] };
    float pr0[1][4] = {{0.f,0.f,0.f,0.f}};
    if (on) quat_pred(&qn0[j*4], p0.x, p0.y, p0.z, p0.w, pr0[0]);
    float c0[1], v0x, v0y, v0z, v0w;
    caps_route8<1>(pr0, aa0, on, c0, v0x, v0y, v0z, v0w);
    float al0 = sigmoidf_(c0[0]*(pr0[0][0]*v0x + pr0[0][1]*v0y
                                + pr0[0][2]*v0z + pr0[0][3]*v0w));

    // gather layer-0 outputs from lanes 0..5
    float pi[6][4], ai[6];
    #pragma unroll
    for (int i = 0; i < 6; i++){
        pi[i][0] = __shfl(v0x, i, 8);
        pi[i][1] = __shfl(v0y, i, 8);
        pi[i][2] = __shfl(v0z, i, 8);
        pi[i][3] = __shfl(v0w, i, 8);
        ai[i]    = __shfl(al0, i, 8);
    }

    // layer 1 (I=6, J=6)
    float pr[6][4];
    #pragma unroll
    for (int i = 0; i < 6; i++){
        pr[i][0]=pr[i][1]=pr[i][2]=pr[i][3]=0.f;
        if (on) quat_pred(&qn1[(i*6+j)*4], pi[i][0], pi[i][1], pi[i][2], pi[i][3], pr[i]);
    }
    float c1[6], v1x, v1y, v1z, v1w;
    caps_route8<6>(pr, ai, on, c1, v1x, v1y, v1z, v1w);
    if (on){
        float acc = 0.f;
        #pragma unroll
        for (int i = 0; i < 6; i++)
            acc += c1[i]*(pr[i][0]*v1x + pr[i][1]*v1y + pr[i][2]*v1z + pr[i][3]*v1w);
        actOut[(size_t)n*6 + j] = sigmoidf_(acc);
        *reinterpret_cast<float4*>(&poseOut[((size_t)n*6 + j)*4]) =
            make_float4(v1x, v1y, v1z, v1w);
    }
    if (j == 0){   // pool1 linked-list build
        float start, size; pool_geom(mm, G, 0, start, size);
        int vid = voxel_id(pos, n, G, start, size);
        vnxt[n] = atomicExch(&vhead[vid], n);
    }
}

// ====== pool1 gather + caps<6,8>, fused per voxel (8 lanes/voxel) ======
__global__ __launch_bounds__(256)
void pool1caps_kernel(const float* __restrict__ poseIn, const float* __restrict__ actIn,
                      const float* __restrict__ pos,
                      const int* __restrict__ head, const int* __restrict__ nxt,
                      const float* __restrict__ q3,
                      float* __restrict__ poseOut, float* __restrict__ actOut,
                      float* __restrict__ posOut, int V){
    __shared__ float qn[48*4];
    for (int t = threadIdx.x; t < 48; t += blockDim.x){
        float qa=q3[t*4],qb=q3[t*4+1],qc=q3[t*4+2],qd=q3[t*4+3];
        float inv=1.f/(sqrtf(qa*qa+qb*qb+qc*qc+qd*qd)+EPS);
        qn[t*4]=qa*inv; qn[t*4+1]=qb*inv; qn[t*4+2]=qc*inv; qn[t*4+3]=qd*inv;
    }
    __syncthreads();
    int tid = blockIdx.x*blockDim.x + threadIdx.x;
    int v = tid >> 3, j = tid & 7;
    if (v >= V) return;          // group-uniform
    bool onj = (j < 6);

    float s0=0.f,s1=0.f,s2=0.f,s3=0.f, w=0.f, ps0=0.f,ps1=0.f,ps2=0.f;
    int cnt = 0;
    for (int n = head[v]; n >= 0; n = nxt[n]){
        if (onj){
            float aj = actIn[(size_t)n*6 + j];
            float4 pb = *reinterpret_cast<const float4*>(&poseIn[((size_t)n*6 + j)*4]);
            s0 += aj*pb.x; s1 += aj*pb.y; s2 += aj*pb.z; s3 += aj*pb.w;
            w += aj;
        } else if (j == 6){
            ps0 += pos[(size_t)n*3+0]; ps1 += pos[(size_t)n*3+1]; ps2 += pos[(size_t)n*3+2];
        }
        cnt++;
    }
    float m0=0.f,m1=0.f,m2=0.f,m3=0.f;
    if (onj){
        float inv = 1.f/(sqrtf(s0*s0+s1*s1+s2*s2+s3*s3)+EPS);
        m0=s0*inv; m1=s1*inv; m2=s2*inv; m3=s3*inv;
    }
    float ag = 0.f;
    for (int n = head[v]; n >= 0; n = nxt[n]){
        if (onj){
            float aj = actIn[(size_t)n*6 + j];
            float4 pb = *reinterpret_cast<const float4*>(&poseIn[((size_t)n*6 + j)*4]);
            ag += aj*(pb.x*m0 + pb.y*m1 + pb.z*m2 + pb.w*m3);
        }
    }
    float actm = sigmoidf_(ag/(w+EPS));   // valid j<6
    if (j == 6){
        float c = (float)cnt + EPS;
        posOut[(size_t)v*3+0] = ps0/c;
        posOut[(size_t)v*3+1] = ps1/c;
        posOut[(size_t)v*3+2] = ps2/c;
    }

    // caps 6 -> 8 (all 8 lanes active)
    float pi[6][4], ai[6];
    #pragma unroll
    for (int i = 0; i < 6; i++){
        pi[i][0] = __shfl(m0, i, 8);
        pi[i][1] = __shfl(m1, i, 8);
        pi[i][2] = __shfl(m2, i, 8);
        pi[i][3] = __shfl(m3, i, 8);
        ai[i]    = __shfl(actm, i, 8);
    }
    float pr[6][4];
    #pragma unroll
    for (int i = 0; i < 6; i++)
        quat_pred(&qn[(i*8+j)*4], pi[i][0], pi[i][1], pi[i][2], pi[i][3], pr[i]);
    float c1[6], vx, vy, vz, vw;
    caps_route8<6>(pr, ai, true, c1, vx, vy, vz, vw);
    float acc = 0.f;
    #pragma unroll
    for (int i = 0; i < 6; i++)
        acc += c1[i]*(pr[i][0]*vx + pr[i][1]*vy + pr[i][2]*vz + pr[i][3]*vw);
    actOut[(size_t)v*8 + j] = sigmoidf_(acc);
    *reinterpret_cast<float4*>(&poseOut[((size_t)v*8 + j)*4]) = make_float4(vx, vy, vz, vw);
}

// ---------- pools 2-3: node-parallel LDS-privatized (proven R3 path) ----------
template<int V, int J, int CH, int NCHUNK>
__global__ void pool_priv1(const float4* __restrict__ poseIn, const float* __restrict__ actIn,
                           const float* __restrict__ posIn,
                           float* __restrict__ s, float* __restrict__ wsum,
                           float* __restrict__ cnt, float* __restrict__ psum,
                           int N, int G, int mode, const unsigned* __restrict__ mm){
    __shared__ float s_[V*CH*4];
    __shared__ float wsum_[V*CH];
    __shared__ float cnt_[V];
    __shared__ float psum_[V*3];
    const int chunk = blockIdx.x % NCHUNK;
    const int slice = blockIdx.x / NCHUNK;
    const int nslices = gridDim.x / NCHUNK;
    const int c0 = chunk * CH;

    for (int t = threadIdx.x; t < V*CH*4; t += blockDim.x) s_[t] = 0.f;
    for (int t = threadIdx.x; t < V*CH; t += blockDim.x) wsum_[t] = 0.f;
    if (chunk == 0){
        for (int t = threadIdx.x; t < V; t += blockDim.x) cnt_[t] = 0.f;
        for (int t = threadIdx.x; t < V*3; t += blockDim.x) psum_[t] = 0.f;
    }
    __syncthreads();

    float start, size; pool_geom(mm, G, mode, start, size);
    int per = (N + nslices - 1) / nslices;
    int n0 = slice * per, n1 = min(N, n0 + per);

    for (int n = n0 + (int)threadIdx.x; n < n1; n += blockDim.x){
        int vid = voxel_id(posIn, n, G, start, size);
        #pragma unroll
        for (int jj = 0; jj < CH; jj++){
            int j = c0 + jj;
            float aj = actIn[(size_t)n*J + j];
            float4 p = poseIn[(size_t)n*J + j];
            int b = (vid*CH + jj)*4;
            atomicAdd(&s_[b+0], aj*p.x);
            atomicAdd(&s_[b+1], aj*p.y);
            atomicAdd(&s_[b+2], aj*p.z);
            atomicAdd(&s_[b+3], aj*p.w);
            atomicAdd(&wsum_[vid*CH + jj], aj);
        }
        if (chunk == 0){
            atomicAdd(&cnt_[vid], 1.0f);
            atomicAdd(&psum_[vid*3+0], posIn[(size_t)n*3+0]);
            atomicAdd(&psum_[vid*3+1], posIn[(size_t)n*3+1]);
            atomicAdd(&psum_[vid*3+2], posIn[(size_t)n*3+2]);
        }
    }
    __syncthreads();

    for (int t = threadIdx.x; t < V*CH*4; t += blockDim.x){
        float val = s_[t];
        if (val != 0.f){
            int v = t / (CH*4), r = t % (CH*4);
            atomicAdd(&s[((size_t)v*J + c0)*4 + r], val);
        }
    }
    for (int t = threadIdx.x; t < V*CH; t += blockDim.x){
        float val = wsum_[t];
        if (val != 0.f){
            int v = t / CH, jj = t % CH;
            atomicAdd(&wsum[(size_t)v*J + c0 + jj], val);
        }
    }
    if (chunk == 0){
        for (int t = threadIdx.x; t < V; t += blockDim.x)
            if (cnt_[t] != 0.f) atomicAdd(&cnt[t], cnt_[t]);
        for (int t = threadIdx.x; t < V*3; t += blockDim.x)
            if (psum_[t] != 0.f) atomicAdd(&psum[t], psum_[t]);
    }
}

template<int V, int J>
__global__ void pool_priv2(const float4* __restrict__ poseIn, const float* __restrict__ actIn,
                           const float* __restrict__ posIn, const float4* __restrict__ m,
                           float* __restrict__ agacc,
                           int N, int G, int mode, const unsigned* __restrict__ mm){
    __shared__ float ag_[V*J];
    for (int t = threadIdx.x; t < V*J; t += blockDim.x) ag_[t] = 0.f;
    __syncthreads();
    float start, size; pool_geom(mm, G, mode, start, size);
    int nslices = gridDim.x;
    int per = (N + nslices - 1) / nslices;
    int n0 = blockIdx.x * per, n1 = min(N, n0 + per);
    for (int n = n0 + (int)threadIdx.x; n < n1; n += blockDim.x){
        int vid = voxel_id(posIn, n, G, start, size);
        #pragma unroll
        for (int j = 0; j < J; j++){
            float4 p  = poseIn[(size_t)n*J + j];
            float4 mv = m[(size_t)vid*J + j];
            float agree = p.x*mv.x + p.y*mv.y + p.z*mv.z + p.w*mv.w;
            atomicAdd(&ag_[vid*J + j], actIn[(size_t)n*J + j]*agree);
        }
    }
    __syncthreads();
    for (int t = threadIdx.x; t < V*J; t += blockDim.x)
        if (ag_[t] != 0.f) atomicAdd(&agacc[t], ag_[t]);
}

// pool_m + pos finalize in one kernel
__global__ void pool_m2(const float* __restrict__ s, float* __restrict__ m,
                        const float* __restrict__ cnt, const float* __restrict__ psum,
                        float* __restrict__ posOut, int V, int J){
    int t = blockIdx.x*blockDim.x + threadIdx.x;
    if (t < V*J){
        float a = s[(size_t)t*4], b = s[(size_t)t*4+1];
        float c = s[(size_t)t*4+2], d = s[(size_t)t*4+3];
        float inv = 1.0f / (sqrtf(a*a + b*b + c*c + d*d) + EPS);
        m[(size_t)t*4]   = a*inv;
        m[(size_t)t*4+1] = b*inv;
        m[(size_t)t*4+2] = c*inv;
        m[(size_t)t*4+3] = d*inv;
    }
    if (t < V){
        float c = cnt[t] + EPS;
        posOut[(size_t)t*3+0] = psum[(size_t)t*3+0] / c;
        posOut[(size_t)t*3+1] = psum[(size_t)t*3+1] / c;
        posOut[(size_t)t*3+2] = psum[(size_t)t*3+2] / c;
    }
}

// ====== cooperative caps with act-finalize fused in prologue ======
template<int I, int J, int NPB>
__global__ __launch_bounds__(NPB*I*J)
void caps_coop_fin(const float* __restrict__ poseIn, const float* __restrict__ agacc,
                   const float* __restrict__ wsum, const float* __restrict__ q,
                   float* __restrict__ poseOut, float* __restrict__ actOut, int N){
    const int IJ = I*J;
    const int tid = threadIdx.x;
    const int nl  = tid / IJ;
    const int li  = tid - nl*IJ;
    const int i   = li / J;
    const int j   = li - i*J;
    const int node = blockIdx.x*NPB + nl;
    const bool on = (node < N);

    __shared__ float redA[NPB][I*J];
    __shared__ float redB[NPB][I*J];
    __shared__ float cp[NPB][I*J*4];
    __shared__ float vsh[NPB][J*4];

    float prx=0.f, pry=0.f, prz=0.f, prw=0.f, ai=0.f;
    if (on){
        float qx = q[li*4+0], qy = q[li*4+1], qz = q[li*4+2], qw = q[li*4+3];
        float qinv = 1.0f/(sqrtf(qx*qx+qy*qy+qz*qz+qw*qw)+EPS);
        qx*=qinv; qy*=qinv; qz*=qinv; qw*=qinv;
        const float* pp = &poseIn[((size_t)node*I + i)*4];
        float rx=pp[0], ry=pp[1], rz=pp[2], rw=pp[3];
        ai = sigmoidf_(agacc[(size_t)node*I + i] / (wsum[(size_t)node*I + i] + EPS));
        float tx = qw*rx + qx*rw + qy*rz - qz*ry;
        float ty = qw*ry - qx*rz + qy*rw + qz*rx;
        float tz = qw*rz + qx*ry - qy*rx + qz*rw;
        float tw = qw*rw - qx*rx - qy*ry - qz*rz;
        float pinv = 1.0f/(sqrtf(tx*tx+ty*ty+tz*tz+tw*tw)+EPS);
        prx=tx*pinv; pry=ty*pinv; prz=tz*pinv; prw=tw*pinv;
    }

    float b = 0.f, c = 0.f;
    for (int t = 0; t < 3; t++){
        redA[nl][li] = b;
        __syncthreads();
        float mb = -INFINITY;
        #pragma unroll
        for (int jj = 0; jj < J; jj++) mb = fmaxf(mb, redA[nl][i*J+jj]);
        float e = expf(b - mb);
        redB[nl][li] = e;
        __syncthreads();
        float s = 0.f;
        #pragma unroll
        for (int jj = 0; jj < J; jj++) s += redB[nl][i*J+jj];
        c = ai * e / s;
        cp[nl][li*4+0] = c*prx; cp[nl][li*4+1] = c*pry;
        cp[nl][li*4+2] = c*prz; cp[nl][li*4+3] = c*prw;
        __syncthreads();
        for (int idx = li; idx < J*4; idx += IJ){
            int jj = idx >> 2, comp = idx & 3;
            float acc = 0.f;
            #pragma unroll
            for (int ii = 0; ii < I; ii++) acc += cp[nl][(ii*J+jj)*4+comp];
            vsh[nl][idx] = acc;
        }
        __syncthreads();
        if (li < J){
            float a0=vsh[nl][li*4], a1=vsh[nl][li*4+1], a2=vsh[nl][li*4+2], a3=vsh[nl][li*4+3];
            float inv = 1.0f/(sqrtf(a0*a0+a1*a1+a2*a2+a3*a3)+EPS);
            vsh[nl][li*4]=a0*inv; vsh[nl][li*4+1]=a1*inv;
            vsh[nl][li*4+2]=a2*inv; vsh[nl][li*4+3]=a3*inv;
        }
        __syncthreads();
        if (t < 2){
            b += prx*vsh[nl][j*4] + pry*vsh[nl][j*4+1] + prz*vsh[nl][j*4+2] + prw*vsh[nl][j*4+3];
            __syncthreads();
        } else {
            redA[nl][li] = c*(prx*vsh[nl][j*4] + pry*vsh[nl][j*4+1]
                            + prz*vsh[nl][j*4+2] + prw*vsh[nl][j*4+3]);
            __syncthreads();
            if (li < J && on){
                float acc = 0.f;
                #pragma unroll
                for (int ii = 0; ii < I; ii++) acc += redA[nl][ii*J+li];
                actOut[(size_t)node*J + li] = sigmoidf_(acc);
                poseOut[((size_t)node*J+li)*4+0] = vsh[nl][li*4+0];
                poseOut[((size_t)node*J+li)*4+1] = vsh[nl][li*4+1];
                poseOut[((size_t)node*J+li)*4+2] = vsh[nl][li*4+2];
                poseOut[((size_t)node*J+li)*4+3] = vsh[nl][li*4+3];
            }
        }
    }
}

// ====== pool4 (8 nodes -> 1 voxel) + final caps<14,10>, one block ======
__global__ __launch_bounds__(192)
void pool4final_kernel(const float* __restrict__ poseIn, const float* __restrict__ actIn,
                       const float* __restrict__ q7, float* __restrict__ out){
    const int NIN = 8, JP = 14, I = 14, J = 10;
    __shared__ float mp[JP*4], ma[JP];
    __shared__ float redA[I*J], redB[I*J], cp[I*J*4], vsh[J*4];
    int t = threadIdx.x;
    if (t < JP){            // pool4: thread-per-capsule, no atomics
        float s0=0.f,s1=0.f,s2=0.f,s3=0.f,w=0.f;
        #pragma unroll
        for (int n = 0; n < NIN; n++){
            float a = actIn[n*JP + t];
            const float* pb = &poseIn[(n*JP + t)*4];
            s0 += a*pb[0]; s1 += a*pb[1]; s2 += a*pb[2]; s3 += a*pb[3];
            w += a;
        }
        float inv = 1.f/(sqrtf(s0*s0+s1*s1+s2*s2+s3*s3)+EPS);
        s0*=inv; s1*=inv; s2*=inv; s3*=inv;
        float ag = 0.f;
        #pragma unroll
        for (int n = 0; n < NIN; n++){
            float a = actIn[n*JP + t];
            const float* pb = &poseIn[(n*JP + t)*4];
            ag += a*(pb[0]*s0 + pb[1]*s1 + pb[2]*s2 + pb[3]*s3);
        }
        ma[t] = sigmoidf_(ag / (w + EPS));
        mp[t*4+0]=s0; mp[t*4+1]=s1; mp[t*4+2]=s2; mp[t*4+3]=s3;
    }
    __syncthreads();

    bool act_thr = (t < I*J);
    int li = act_thr ? t : 0;
    int i = li / J, j = li % J;
    float prx=0.f, pry=0.f, prz=0.f, prw=0.f, ai=0.f;
    if (act_thr){
        float qx=q7[li*4],qy=q7[li*4+1],qz=q7[li*4+2],qw=q7[li*4+3];
        float qinv = 1.f/(sqrtf(qx*qx+qy*qy+qz*qz+qw*qw)+EPS);
        qx*=qinv; qy*=qinv; qz*=qinv; qw*=qinv;
        float rx=mp[i*4], ry=mp[i*4+1], rz=mp[i*4+2], rw=mp[i*4+3];
        ai = ma[i];
        float tx = qw*rx + qx*rw + qy*rz - qz*ry;
        float ty = qw*ry - qx*rz + qy*rw + qz*rx;
        float tz = qw*rz + qx*ry - qy*rx + qz*rw;
        float tw = qw*rw - qx*rx - qy*ry - qz*rz;
        float pinv = 1.f/(sqrtf(tx*tx+ty*ty+tz*tz+tw*tw)+EPS);
        prx=tx*pinv; pry=ty*pinv; prz=tz*pinv; prw=tw*pinv;
    }
    float b = 0.f, c = 0.f;
    for (int it = 0; it < 3; it++){
        if (act_thr) redA[li] = b;
        __syncthreads();
        float mb = -INFINITY;
        #pragma unroll
        for (int jj = 0; jj < J; jj++) mb = fmaxf(mb, redA[i*J+jj]);
        float e = expf(b - mb);
        if (act_thr) redB[li] = e;
        __syncthreads();
        float s = 0.f;
        #pragma unroll
        for (int jj = 0; jj < J; jj++) s += redB[i*J+jj];
        c = ai * e / s;
        if (act_thr){
            cp[li*4+0]=c*prx; cp[li*4+1]=c*pry; cp[li*4+2]=c*prz; cp[li*4+3]=c*prw;
        }
        __syncthreads();
        if (act_thr){
            for (int idx = li; idx < J*4; idx += I*J){
                int jj = idx >> 2, comp = idx & 3;
                float acc = 0.f;
                #pragma unroll
                for (int ii = 0; ii < I; ii++) acc += cp[(ii*J+jj)*4+comp];
                vsh[idx] = acc;
            }
        }
        __syncthreads();
        if (act_thr && li < J){
            float a0=vsh[li*4], a1=vsh[li*4+1], a2=vsh[li*4+2], a3=vsh[li*4+3];
            float inv = 1.f/(sqrtf(a0*a0+a1*a1+a2*a2+a3*a3)+EPS);
            vsh[li*4]=a0*inv; vsh[li*4+1]=a1*inv; vsh[li*4+2]=a2*inv; vsh[li*4+3]=a3*inv;
        }
        __syncthreads();
        if (it < 2){
            b += prx*vsh[j*4] + pry*vsh[j*4+1] + prz*vsh[j*4+2] + prw*vsh[j*4+3];
            __syncthreads();
        } else {
            if (act_thr)
                redA[li] = c*(prx*vsh[j*4] + pry*vsh[j*4+1]
                            + prz*vsh[j*4+2] + prw*vsh[j*4+3]);
            __syncthreads();
            if (act_thr && li < J){
                float acc = 0.f;
                #pragma unroll
                for (int ii = 0; ii < I; ii++) acc += redA[ii*J+li];
                out[li] = sigmoidf_(acc);
            }
        }
    }
}

extern "C" void kernel_launch(void* const* d_in, const int* in_sizes, int n_in,
                              void* d_out, int out_size, void* d_ws, size_t ws_size,
                              hipStream_t stream){
    const float* x      = (const float*)d_in[0];
    const float* pos    = (const float*)d_in[1];
    const float* pseudo = (const float*)d_in[2];
    const float* Wsp    = (const float*)d_in[3];
    const float* root   = (const float*)d_in[4];
    const float* bias   = (const float*)d_in[5];
    const float* lin_w  = (const float*)d_in[6];
    const float* lin_b  = (const float*)d_in[7];
    const float* q0     = (const float*)d_in[8];
    const float* q1     = (const float*)d_in[9];
    const float* q3     = (const float*)d_in[10];
    const float* q5     = (const float*)d_in[11];
    const float* q6     = (const float*)d_in[12];
    const float* q7     = (const float*)d_in[13];
    const int*   ei     = (const int*)d_in[14];
    const int N = in_sizes[0];
    const int E = in_sizes[2] / 3;
    const int V1 = 32768;
    const int NB = (N + 255)/256;

    char* ws = (char*)d_ws;
    size_t off = 0;
    auto alloc = [&](size_t bytes)->void*{
        void* p = ws + off;
        off += (bytes + 255) & ~(size_t)255;
        return p;
    };
    unsigned* mm   = (unsigned*)alloc(8);
    int* deg       = (int*)alloc((size_t)N*sizeof(int));
    int* eoff      = (int*)alloc((size_t)(N+1)*sizeof(int));
    int* bsum      = (int*)alloc((size_t)(NB+1)*sizeof(int));
    float4* rec4   = (float4*)alloc((size_t)E*sizeof(float4));
    int* recb      = (int*)alloc((size_t)E*sizeof(int));
    int* vhead     = (int*)alloc((size_t)V1*sizeof(int));
    int* vnxt      = (int*)alloc((size_t)N*sizeof(int));
    float* P0  = (float*)alloc((size_t)1250000*sizeof(float));
    float* P1  = (float*)alloc((size_t)1250000*sizeof(float));
    float* A0  = (float*)alloc((size_t)310000*sizeof(float));
    float* A1  = (float*)alloc((size_t)310000*sizeof(float));
    float* PB0 = (float*)alloc((size_t)100000*sizeof(float));
    float* PB1 = (float*)alloc((size_t)100000*sizeof(float));
    size_t z0 = off;                                // zeroed pool-scratch region start
    float* vs2 = (float*)alloc((size_t)512*8*4*sizeof(float));
    float* vw2 = (float*)alloc((size_t)512*8*sizeof(float));
    float* va2 = (float*)alloc((size_t)512*8*sizeof(float));
    float* vc2 = (float*)alloc((size_t)512*sizeof(float));
    float* vp2 = (float*)alloc((size_t)512*3*sizeof(float));
    float* vs3 = (float*)alloc((size_t)8*12*4*sizeof(float));
    float* vw3 = (float*)alloc((size_t)8*12*sizeof(float));
    float* va3 = (float*)alloc((size_t)8*12*sizeof(float));
    float* vc3 = (float*)alloc((size_t)8*sizeof(float));
    float* vp3 = (float*)alloc((size_t)8*3*sizeof(float));
    size_t z1 = off;
    float* pzero = (float*)(ws + z0);
    const int PZ = (int)((z1 - z0)/sizeof(float));  // zero whole region incl. padding

    // 18 dispatches; CSR build now has ZERO global atomics.
    init_kernel<<<128, 256, 0, stream>>>(mm, vhead, V1, pzero, PZ);
    deg_hist<<<DEGB, 1024, 0, stream>>>(pos, N*3, mm, ei, deg, E, N);
    scan_bsum<<<NB, 256, 0, stream>>>(deg, bsum, N);
    scan_top<<<1, 1024, 0, stream>>>(bsum, NB);
    scan_final<<<NB, 256, 0, stream>>>(deg, bsum, eoff, N, NB);
    edge_pack2<<<DEGB, 1024, 0, stream>>>(ei, pseudo, x, eoff, rec4, recb, E, N);
    spline_node_kernel<<<(8*N + 255)/256, 256, 0, stream>>>(x, rec4, recb, eoff, Wsp,
                                                            root, bias, lin_w, lin_b, P0, A0, N);

    // caps<1,6> + caps<6,6> + pool1 list build, fused
    caps01_kernel<<<(8*N + 255)/256, 256, 0, stream>>>(P0, A0, q0, q1, P1, A1,
                                                       pos, vhead, vnxt, N, 32, mm);
    // pool1 gather + caps<6,8>, fused
    pool1caps_kernel<<<(8*V1 + 255)/256, 256, 0, stream>>>(P1, A1, pos, vhead, vnxt,
                                                           q3, P0, A0, PB0, V1);

    // pool2: 32768 -> 512 (G=8), J=8
    pool_priv1<512,8,4,2><<<128, 256, 0, stream>>>((const float4*)P0, A0, PB0,
                                                   vs2, vw2, vc2, vp2, 32768, 8, 0, mm);
    pool_m2<<<16, 256, 0, stream>>>(vs2, P1, vc2, vp2, PB1, 512, 8);
    pool_priv2<512,8><<<64, 256, 0, stream>>>((const float4*)P0, A0, PB0,
                                              (const float4*)P1, va2, 32768, 8, 0, mm);
    caps_coop_fin<8,12,2><<<256, 2*96, 0, stream>>>(P1, va2, vw2, q5, P0, A0, 512);

    // pool3: 512 -> 8 (G=2), J=12
    pool_priv1<8,12,12,1><<<16, 256, 0, stream>>>((const float4*)P0, A0, PB1,
                                                  vs3, vw3, vc3, vp3, 512, 2, 0, mm);
    pool_m2<<<1, 256, 0, stream>>>(vs3, P1, vc3, vp3, PB0, 8, 12);
    pool_priv2<8,12><<<16, 256, 0, stream>>>((const float4*)P0, A0, PB1,
                                             (const float4*)P1, va3, 512, 2, 0, mm);
    caps_coop_fin<12,14,1><<<8, 168, 0, stream>>>(P1, va3, vw3, q6, P0, A0, 8);

    // pool4 + final caps<14,10>, fused single block -> d_out
    pool4final_kernel<<<1, 192, 0, stream>>>(P0, A0, q7, (float*)d_out);
}

// Round 10
// 329.227 us; speedup vs baseline: 2.7257x; 2.7257x over previous
//
#include <hip/hip_runtime.h>
#include <math.h>

#define EPS 1e-4f

__device__ __forceinline__ float sigmoidf_(float x){ return 1.0f/(1.0f+expf(-x)); }

// ---- ordered-uint mapping for float atomic min/max ----
__device__ __forceinline__ unsigned f2u_(float f){
    unsigned u = __float_as_uint(f);
    return (u & 0x80000000u) ? ~u : (u | 0x80000000u);
}
__device__ __forceinline__ float u2f_(unsigned u){
    unsigned b = (u & 0x80000000u) ? (u & 0x7FFFFFFFu) : ~u;
    return __uint_as_float(b);
}

// ================= init: all memsets in one launch =================
__global__ void init_kernel(unsigned* __restrict__ mm, int* __restrict__ deg, int N,
                            int* __restrict__ vhead, int V,
                            float* __restrict__ pz, int PZ){
    int i = blockIdx.x*blockDim.x + threadIdx.x;
    int stride = gridDim.x*blockDim.x;
    if (i == 0){ mm[0] = 0xFFFFFFFFu; mm[1] = 0u; }
    for (int t = i; t < N; t += stride) deg[t] = 0;
    for (int t = i; t < V; t += stride) vhead[t] = -1;
    for (int t = i; t < PZ; t += stride) pz[t] = 0.f;
}

// ================= prep: minmax(pos) + edge_rank fused (R8-proven) =================
// R9 lesson: the "atomic-free" rescan build multiplied work 128x (435us). The 800K
// device-scope atomicAdds (~44us memory-side) are the cheapest known deg+rank build.
// Grid raised 512->2048 blocks: prep is bound by in-flight atomic round-trips, so 4x
// waves = 4x outstanding atomics (neutral if the atomic unit is already saturated).
__global__ void prep_kernel(const float* __restrict__ p, int n3, unsigned* mm,
                            const int* __restrict__ ei, int* __restrict__ deg,
                            int* __restrict__ rank, int E){
    int gid = blockIdx.x*blockDim.x + threadIdx.x;
    int stride = gridDim.x*blockDim.x;
    float lo = INFINITY, hi = -INFINITY;
    for (int i = gid; i < n3; i += stride){
        float v = p[i]; lo = fminf(lo, v); hi = fmaxf(hi, v);
    }
    for (int off = 32; off > 0; off >>= 1){
        lo = fminf(lo, __shfl_down(lo, off));
        hi = fmaxf(hi, __shfl_down(hi, off));
    }
    __shared__ float slo[4], shi[4];
    int wid = threadIdx.x >> 6;
    if ((threadIdx.x & 63) == 0){ slo[wid] = lo; shi[wid] = hi; }
    __syncthreads();
    if (threadIdx.x == 0){
        for (int w = 1; w < 4; w++){ lo = fminf(lo, slo[w]); hi = fmaxf(hi, shi[w]); }
        atomicMin(&mm[0], f2u_(lo));
        atomicMax(&mm[1], f2u_(hi));
    }
    for (int e = gid; e < E; e += stride)
        rank[e] = atomicAdd(&deg[ei[E + e]], 1);
}

// ================= CSR scan: per-block sums, then fused final =================
__global__ __launch_bounds__(256)
void scan_bsum(const int* __restrict__ deg, int* __restrict__ bsum, int N){
    int i = blockIdx.x*256 + threadIdx.x;
    int v = (i < N) ? deg[i] : 0;
    for (int o = 32; o > 0; o >>= 1) v += __shfl_down(v, o);
    __shared__ int ws[4];
    if ((threadIdx.x & 63) == 0) ws[threadIdx.x >> 6] = v;
    __syncthreads();
    if (threadIdx.x == 0) bsum[blockIdx.x] = ws[0] + ws[1] + ws[2] + ws[3];
}

// scan_top folded in: every block redundantly scans the <=256 raw block-sums in LDS
// (parallel, ~us) -- saves one launch+gap vs the 3-kernel scan. bsum stays unmutated.
__global__ __launch_bounds__(256)
void scan_final2(const int* __restrict__ deg, const int* __restrict__ bsum,
                 int* __restrict__ off, int N, int NB){
    __shared__ int sh[256], top[256];
    int b = blockIdx.x;
    int t = threadIdx.x;
    int bv = (t < NB) ? bsum[t] : 0;
    top[t] = bv;
    __syncthreads();
    for (int d = 1; d < 256; d <<= 1){
        int u = (t >= d) ? top[t - d] : 0;
        __syncthreads();
        top[t] += u;
        __syncthreads();
    }
    int i = b*256 + t;
    int v = (i < N) ? deg[i] : 0;
    sh[t] = v;
    __syncthreads();
    for (int d = 1; d < 256; d <<= 1){
        int u = (t >= d) ? sh[t - d] : 0;
        __syncthreads();
        sh[t] += u;
        __syncthreads();
    }
    int pre = (b == 0) ? 0 : top[b-1];
    if (i < N) off[i] = pre + sh[t] - v;                  // exclusive
    if (b == 0 && t == 0) off[N] = top[NB-1];
}

// streaming pack + atomic-free scatter: slot = off[dst] + rank[e]  (R8-proven)
__global__ void edge_pack(const int* __restrict__ ei, const float* __restrict__ pseudo,
                          const float* __restrict__ x,
                          const int* __restrict__ rank, const int* __restrict__ off,
                          float4* __restrict__ rec4, int* __restrict__ recb, int E){
    int e = blockIdx.x*blockDim.x + threadIdx.x;
    if (e >= E) return;
    float p0 = pseudo[3*e], p1 = pseudo[3*e+1], p2 = pseudo[3*e+2];
    int s = ei[e], d = ei[E + e];
    float v0 = p0*4.f, v1 = p1*4.f, v2 = p2*4.f;
    float f0 = fminf(fmaxf(floorf(v0), 0.f), 3.f);
    float f1 = fminf(fmaxf(floorf(v1), 0.f), 3.f);
    float f2 = fminf(fmaxf(floorf(v2), 0.f), 3.f);
    int slot = off[d] + rank[e];
    rec4[slot] = make_float4(v0 - f0, v1 - f1, v2 - f2, x[s]);
    recb[slot] = ((int)f0*5 + (int)f1)*5 + (int)f2;
}

__device__ __forceinline__ int voxel_id(const float* __restrict__ pos, int n, int G,
                                        float start, float size){
    int g[3];
    #pragma unroll
    for (int k = 0; k < 3; k++){
        float gg = floorf((pos[(size_t)n*3 + k] - start) / size);
        gg = fminf(fmaxf(gg, 0.f), (float)(G - 1));
        g[k] = (int)gg;
    }
    return (g[0]*G + g[1])*G + g[2];
}

__device__ __forceinline__ void pool_geom(const unsigned* mm, int G, int mode,
                                          float& start, float& size){
    float mn = u2f_(mm[0]), mx = u2f_(mm[1]);
    if (mode == 0){ start = mn; size = (mx + 0.001f - mn) / (float)G; }
    else          { start = mn - 0.5f; size = mx - mn + 1.0f; }
}

// ===== fused spline gather + node finalize: 8 lanes per node (tid = n*8+k) =====
__global__ __launch_bounds__(256)
void spline_node_kernel(const float* __restrict__ x, const float4* __restrict__ rec4,
                        const int* __restrict__ recb, const int* __restrict__ off,
                        const float* __restrict__ W,
                        const float* __restrict__ root, const float* __restrict__ bias,
                        const float* __restrict__ lin_w, const float* __restrict__ lin_b,
                        float* __restrict__ pose, float* __restrict__ act, int N){
    __shared__ float Ws[125*17];
    for (int i = threadIdx.x; i < 125*16; i += blockDim.x)
        Ws[(i >> 4)*17 + (i & 15)] = W[i];
    __syncthreads();
    int t = blockIdx.x*blockDim.x + threadIdx.x;
    int n = t >> 3;
    int k = t & 7;
    if (n >= N) return;     // group-uniform guard (all 8 lanes share n)

    int o0 = off[n], o1 = off[n+1];

    float agg[16];
    #pragma unroll
    for (int o = 0; o < 16; o++) agg[o] = 0.f;

    for (int s = o0 + k; s < o1; s += 8){
        float4 rv = rec4[s];
        int base = recb[s];
        float fr0 = rv.x, fr1 = rv.y, fr2 = rv.z, xv = rv.w;
        #pragma unroll
        for (int b = 0; b < 8; b++){
            int b0 = (b >> 2) & 1, b1 = (b >> 1) & 1, b2 = b & 1;
            float w = (b0 ? fr0 : 1.f - fr0) * (b1 ? fr1 : 1.f - fr1) * (b2 ? fr2 : 1.f - fr2);
            w *= xv;
            const float* Wr = &Ws[(base + b0*25 + b1*5 + b2)*17];
            #pragma unroll
            for (int o = 0; o < 16; o++) agg[o] += w * Wr[o];
        }
    }

    #pragma unroll
    for (int o = 0; o < 16; o++){
        agg[o] += __shfl_xor(agg[o], 1);
        agg[o] += __shfl_xor(agg[o], 2);
        agg[o] += __shfl_xor(agg[o], 4);
    }

    if (k != 0) return;

    float deg = fmaxf((float)(o1 - o0), 1.0f);
    float xs = x[n];
    float qv0 = lin_b[0], qv1 = lin_b[1], qv2 = lin_b[2], qv3 = lin_b[3];
    #pragma unroll
    for (int o = 0; o < 16; o++){
        float h = agg[o] / deg + xs * root[o] + bias[o];
        float e = (h > 0.f) ? h : expm1f(h);
        qv0 += e * lin_w[o*4 + 0];
        qv1 += e * lin_w[o*4 + 1];
        qv2 += e * lin_w[o*4 + 2];
        qv3 += e * lin_w[o*4 + 3];
    }
    float inv = 1.0f / (sqrtf(qv0*qv0 + qv1*qv1 + qv2*qv2 + qv3*qv3) + EPS);
    pose[(size_t)n*4 + 0] = qv0*inv;
    pose[(size_t)n*4 + 1] = qv1*inv;
    pose[(size_t)n*4 + 2] = qv2*inv;
    pose[(size_t)n*4 + 3] = qv3*inv;
    act[n] = xs;
}

// ====== wave-level routing core (R6-verified math, 8-lane group) ======
__device__ __forceinline__ void quat_pred(const float* qq, float px, float py, float pz,
                                          float pw, float* pr){
    float qx=qq[0], qy=qq[1], qz=qq[2], qw=qq[3];
    float tx = qw*px + qx*pw + qy*pz - qz*py;
    float ty = qw*py - qx*pz + qy*pw + qz*px;
    float tz = qw*pz + qx*py - qy*px + qz*pw;
    float tw = qw*pw - qx*px - qy*py - qz*pz;
    float inv = 1.f/(sqrtf(tx*tx+ty*ty+tz*tz+tw*tw)+EPS);
    pr[0]=tx*inv; pr[1]=ty*inv; pr[2]=tz*inv; pr[3]=tw*inv;
}

template<int I>
__device__ __forceinline__ void caps_route8(const float (*pr)[4], const float* a, bool on,
                                            float* c, float& v0, float& v1,
                                            float& v2, float& v3){
    float b[I];
    #pragma unroll
    for (int i = 0; i < I; i++) b[i] = on ? 0.f : -INFINITY;
    v0=v1=v2=v3=0.f;
    #pragma unroll
    for (int t = 0; t < 3; t++){
        #pragma unroll
        for (int i = 0; i < I; i++){
            float mb = b[i];
            mb = fmaxf(mb, __shfl_xor(mb, 1));
            mb = fmaxf(mb, __shfl_xor(mb, 2));
            mb = fmaxf(mb, __shfl_xor(mb, 4));
            float e = on ? expf(b[i] - mb) : 0.f;
            float s = e;
            s += __shfl_xor(s, 1);
            s += __shfl_xor(s, 2);
            s += __shfl_xor(s, 4);
            c[i] = a[i] * e / s;
        }
        float s0=0.f, s1=0.f, s2=0.f, s3=0.f;
        #pragma unroll
        for (int i = 0; i < I; i++){
            s0 += c[i]*pr[i][0]; s1 += c[i]*pr[i][1];
            s2 += c[i]*pr[i][2]; s3 += c[i]*pr[i][3];
        }
        float inv = 1.f/(sqrtf(s0*s0+s1*s1+s2*s2+s3*s3)+EPS);
        v0=s0*inv; v1=s1*inv; v2=s2*inv; v3=s3*inv;
        if (t < 2){
            #pragma unroll
            for (int i = 0; i < I; i++)
                b[i] += pr[i][0]*v0 + pr[i][1]*v1 + pr[i][2]*v2 + pr[i][3]*v3;
        }
    }
}

// ====== caps<1,6> + caps<6,6> + pool1 elist build, fused per node ======
__global__ __launch_bounds__(256)
void caps01_kernel(const float* __restrict__ pose0, const float* __restrict__ act0,
                   const float* __restrict__ q0, const float* __restrict__ q1,
                   float* __restrict__ poseOut, float* __restrict__ actOut,
                   const float* __restrict__ pos, int* __restrict__ vhead,
                   int* __restrict__ vnxt, int N, int G,
                   const unsigned* __restrict__ mm){
    __shared__ float qn0[6*4], qn1[36*4];
    for (int t = threadIdx.x; t < 6; t += blockDim.x){
        float qa=q0[t*4],qb=q0[t*4+1],qc=q0[t*4+2],qd=q0[t*4+3];
        float inv=1.f/(sqrtf(qa*qa+qb*qb+qc*qc+qd*qd)+EPS);
        qn0[t*4]=qa*inv; qn0[t*4+1]=qb*inv; qn0[t*4+2]=qc*inv; qn0[t*4+3]=qd*inv;
    }
    for (int t = threadIdx.x; t < 36; t += blockDim.x){
        float qa=q1[t*4],qb=q1[t*4+1],qc=q1[t*4+2],qd=q1[t*4+3];
        float inv=1.f/(sqrtf(qa*qa+qb*qb+qc*qc+qd*qd)+EPS);
        qn1[t*4]=qa*inv; qn1[t*4+1]=qb*inv; qn1[t*4+2]=qc*inv; qn1[t*4+3]=qd*inv;
    }
    __syncthreads();
    int tid = blockIdx.x*blockDim.x + threadIdx.x;
    int n = tid >> 3, j = tid & 7;
    if (n >= N) return;          // group-uniform
    bool on = (j < 6);

    // layer 0 (I=1, J=6)
    float4 p0 = *reinterpret_cast<const float4*>(&pose0[(size_t)n*4]);
    float aa0[1] = { act0[n] };
    float pr0[1][4] = {{0.f,0.f,0.f,0.f}};
    if (on) quat_pred(&qn0[j*4], p0.x, p0.y, p0.z, p0.w, pr0[0]);
    float c0[1], v0x, v0y, v0z, v0w;
    caps_route8<1>(pr0, aa0, on, c0, v0x, v0y, v0z, v0w);
    float al0 = sigmoidf_(c0[0]*(pr0[0][0]*v0x + pr0[0][1]*v0y
                                + pr0[0][2]*v0z + pr0[0][3]*v0w));

    // gather layer-0 outputs from lanes 0..5
    float pi[6][4], ai[6];
    #pragma unroll
    for (int i = 0; i < 6; i++){
        pi[i][0] = __shfl(v0x, i, 8);
        pi[i][1] = __shfl(v0y, i, 8);
        pi[i][2] = __shfl(v0z, i, 8);
        pi[i][3] = __shfl(v0w, i, 8);
        ai[i]    = __shfl(al0, i, 8);
    }

    // layer 1 (I=6, J=6)
    float pr[6][4];
    #pragma unroll
    for (int i = 0; i < 6; i++){
        pr[i][0]=pr[i][1]=pr[i][2]=pr[i][3]=0.f;
        if (on) quat_pred(&qn1[(i*6+j)*4], pi[i][0], pi[i][1], pi[i][2], pi[i][3], pr[i]);
    }
    float c1[6], v1x, v1y, v1z, v1w;
    caps_route8<6>(pr, ai, on, c1, v1x, v1y, v1z, v1w);
    if (on){
        float acc = 0.f;
        #pragma unroll
        for (int i = 0; i < 6; i++)
            acc += c1[i]*(pr[i][0]*v1x + pr[i][1]*v1y + pr[i][2]*v1z + pr[i][3]*v1w);
        actOut[(size_t)n*6 + j] = sigmoidf_(acc);
        *reinterpret_cast<float4*>(&poseOut[((size_t)n*6 + j)*4]) =
            make_float4(v1x, v1y, v1z, v1w);
    }
    if (j == 0){   // pool1 linked-list build
        float start, size; pool_geom(mm, G, 0, start, size);
        int vid = voxel_id(pos, n, G, start, size);
        vnxt[n] = atomicExch(&vhead[vid], n);
    }
}

// ====== pool1 gather + caps<6,8>, fused per voxel (8 lanes/voxel) ======
__global__ __launch_bounds__(256)
void pool1caps_kernel(const float* __restrict__ poseIn, const float* __restrict__ actIn,
                      const float* __restrict__ pos,
                      const int* __restrict__ head, const int* __restrict__ nxt,
                      const float* __restrict__ q3,
                      float* __restrict__ poseOut, float* __restrict__ actOut,
                      float* __restrict__ posOut, int V){
    __shared__ float qn[48*4];
    for (int t = threadIdx.x; t < 48; t += blockDim.x){
        float qa=q3[t*4],qb=q3[t*4+1],qc=q3[t*4+2],qd=q3[t*4+3];
        float inv=1.f/(sqrtf(qa*qa+qb*qb+qc*qc+qd*qd)+EPS);
        qn[t*4]=qa*inv; qn[t*4+1]=qb*inv; qn[t*4+2]=qc*inv; qn[t*4+3]=qd*inv;
    }
    __syncthreads();
    int tid = blockIdx.x*blockDim.x + threadIdx.x;
    int v = tid >> 3, j = tid & 7;
    if (v >= V) return;          // group-uniform
    bool onj = (j < 6);

    float s0=0.f,s1=0.f,s2=0.f,s3=0.f, w=0.f, ps0=0.f,ps1=0.f,ps2=0.f;
    int cnt = 0;
    for (int n = head[v]; n >= 0; n = nxt[n]){
        if (onj){
            float aj = actIn[(size_t)n*6 + j];
            float4 pb = *reinterpret_cast<const float4*>(&poseIn[((size_t)n*6 + j)*4]);
            s0 += aj*pb.x; s1 += aj*pb.y; s2 += aj*pb.z; s3 += aj*pb.w;
            w += aj;
        } else if (j == 6){
            ps0 += pos[(size_t)n*3+0]; ps1 += pos[(size_t)n*3+1]; ps2 += pos[(size_t)n*3+2];
        }
        cnt++;
    }
    float m0=0.f,m1=0.f,m2=0.f,m3=0.f;
    if (onj){
        float inv = 1.f/(sqrtf(s0*s0+s1*s1+s2*s2+s3*s3)+EPS);
        m0=s0*inv; m1=s1*inv; m2=s2*inv; m3=s3*inv;
    }
    float ag = 0.f;
    for (int n = head[v]; n >= 0; n = nxt[n]){
        if (onj){
            float aj = actIn[(size_t)n*6 + j];
            float4 pb = *reinterpret_cast<const float4*>(&poseIn[((size_t)n*6 + j)*4]);
            ag += aj*(pb.x*m0 + pb.y*m1 + pb.z*m2 + pb.w*m3);
        }
    }
    float actm = sigmoidf_(ag/(w+EPS));   // valid j<6
    if (j == 6){
        float c = (float)cnt + EPS;
        posOut[(size_t)v*3+0] = ps0/c;
        posOut[(size_t)v*3+1] = ps1/c;
        posOut[(size_t)v*3+2] = ps2/c;
    }

    // caps 6 -> 8 (all 8 lanes active)
    float pi[6][4], ai[6];
    #pragma unroll
    for (int i = 0; i < 6; i++){
        pi[i][0] = __shfl(m0, i, 8);
        pi[i][1] = __shfl(m1, i, 8);
        pi[i][2] = __shfl(m2, i, 8);
        pi[i][3] = __shfl(m3, i, 8);
        ai[i]    = __shfl(actm, i, 8);
    }
    float pr[6][4];
    #pragma unroll
    for (int i = 0; i < 6; i++)
        quat_pred(&qn[(i*8+j)*4], pi[i][0], pi[i][1], pi[i][2], pi[i][3], pr[i]);
    float c1[6], vx, vy, vz, vw;
    caps_route8<6>(pr, ai, true, c1, vx, vy, vz, vw);
    float acc = 0.f;
    #pragma unroll
    for (int i = 0; i < 6; i++)
        acc += c1[i]*(pr[i][0]*vx + pr[i][1]*vy + pr[i][2]*vz + pr[i][3]*vw);
    actOut[(size_t)v*8 + j] = sigmoidf_(acc);
    *reinterpret_cast<float4*>(&poseOut[((size_t)v*8 + j)*4]) = make_float4(vx, vy, vz, vw);
}

// ---------- pools 2-3: node-parallel LDS-privatized (proven R3 path) ----------
template<int V, int J, int CH, int NCHUNK>
__global__ void pool_priv1(const float4* __restrict__ poseIn, const float* __restrict__ actIn,
                           const float* __restrict__ posIn,
                           float* __restrict__ s, float* __restrict__ wsum,
                           float* __restrict__ cnt, float* __restrict__ psum,
                           int N, int G, int mode, const unsigned* __restrict__ mm){
    __shared__ float s_[V*CH*4];
    __shared__ float wsum_[V*CH];
    __shared__ float cnt_[V];
    __shared__ float psum_[V*3];
    const int chunk = blockIdx.x % NCHUNK;
    const int slice = blockIdx.x / NCHUNK;
    const int nslices = gridDim.x / NCHUNK;
    const int c0 = chunk * CH;

    for (int t = threadIdx.x; t < V*CH*4; t += blockDim.x) s_[t] = 0.f;
    for (int t = threadIdx.x; t < V*CH; t += blockDim.x) wsum_[t] = 0.f;
    if (chunk == 0){
        for (int t = threadIdx.x; t < V; t += blockDim.x) cnt_[t] = 0.f;
        for (int t = threadIdx.x; t < V*3; t += blockDim.x) psum_[t] = 0.f;
    }
    __syncthreads();

    float start, size; pool_geom(mm, G, mode, start, size);
    int per = (N + nslices - 1) / nslices;
    int n0 = slice * per, n1 = min(N, n0 + per);

    for (int n = n0 + (int)threadIdx.x; n < n1; n += blockDim.x){
        int vid = voxel_id(posIn, n, G, start, size);
        #pragma unroll
        for (int jj = 0; jj < CH; jj++){
            int j = c0 + jj;
            float aj = actIn[(size_t)n*J + j];
            float4 p = poseIn[(size_t)n*J + j];
            int b = (vid*CH + jj)*4;
            atomicAdd(&s_[b+0], aj*p.x);
            atomicAdd(&s_[b+1], aj*p.y);
            atomicAdd(&s_[b+2], aj*p.z);
            atomicAdd(&s_[b+3], aj*p.w);
            atomicAdd(&wsum_[vid*CH + jj], aj);
        }
        if (chunk == 0){
            atomicAdd(&cnt_[vid], 1.0f);
            atomicAdd(&psum_[vid*3+0], posIn[(size_t)n*3+0]);
            atomicAdd(&psum_[vid*3+1], posIn[(size_t)n*3+1]);
            atomicAdd(&psum_[vid*3+2], posIn[(size_t)n*3+2]);
        }
    }
    __syncthreads();

    for (int t = threadIdx.x; t < V*CH*4; t += blockDim.x){
        float val = s_[t];
        if (val != 0.f){
            int v = t / (CH*4), r = t % (CH*4);
            atomicAdd(&s[((size_t)v*J + c0)*4 + r], val);
        }
    }
    for (int t = threadIdx.x; t < V*CH; t += blockDim.x){
        float val = wsum_[t];
        if (val != 0.f){
            int v = t / CH, jj = t % CH;
            atomicAdd(&wsum[(size_t)v*J + c0 + jj], val);
        }
    }
    if (chunk == 0){
        for (int t = threadIdx.x; t < V; t += blockDim.x)
            if (cnt_[t] != 0.f) atomicAdd(&cnt[t], cnt_[t]);
        for (int t = threadIdx.x; t < V*3; t += blockDim.x)
            if (psum_[t] != 0.f) atomicAdd(&psum[t], psum_[t]);
    }
}

template<int V, int J>
__global__ void pool_priv2(const float4* __restrict__ poseIn, const float* __restrict__ actIn,
                           const float* __restrict__ posIn, const float4* __restrict__ m,
                           float* __restrict__ agacc,
                           int N, int G, int mode, const unsigned* __restrict__ mm){
    __shared__ float ag_[V*J];
    for (int t = threadIdx.x; t < V*J; t += blockDim.x) ag_[t] = 0.f;
    __syncthreads();
    float start, size; pool_geom(mm, G, mode, start, size);
    int nslices = gridDim.x;
    int per = (N + nslices - 1) / nslices;
    int n0 = blockIdx.x * per, n1 = min(N, n0 + per);
    for (int n = n0 + (int)threadIdx.x; n < n1; n += blockDim.x){
        int vid = voxel_id(posIn, n, G, start, size);
        #pragma unroll
        for (int j = 0; j < J; j++){
            float4 p  = poseIn[(size_t)n*J + j];
            float4 mv = m[(size_t)vid*J + j];
            float agree = p.x*mv.x + p.y*mv.y + p.z*mv.z + p.w*mv.w;
            atomicAdd(&ag_[vid*J + j], actIn[(size_t)n*J + j]*agree);
        }
    }
    __syncthreads();
    for (int t = threadIdx.x; t < V*J; t += blockDim.x)
        if (ag_[t] != 0.f) atomicAdd(&agacc[t], ag_[t]);
}

// pool_m + pos finalize in one kernel
__global__ void pool_m2(const float* __restrict__ s, float* __restrict__ m,
                        const float* __restrict__ cnt, const float* __restrict__ psum,
                        float* __restrict__ posOut, int V, int J){
    int t = blockIdx.x*blockDim.x + threadIdx.x;
    if (t < V*J){
        float a = s[(size_t)t*4], b = s[(size_t)t*4+1];
        float c = s[(size_t)t*4+2], d = s[(size_t)t*4+3];
        float inv = 1.0f / (sqrtf(a*a + b*b + c*c + d*d) + EPS);
        m[(size_t)t*4]   = a*inv;
        m[(size_t)t*4+1] = b*inv;
        m[(size_t)t*4+2] = c*inv;
        m[(size_t)t*4+3] = d*inv;
    }
    if (t < V){
        float c = cnt[t] + EPS;
        posOut[(size_t)t*3+0] = psum[(size_t)t*3+0] / c;
        posOut[(size_t)t*3+1] = psum[(size_t)t*3+1] / c;
        posOut[(size_t)t*3+2] = psum[(size_t)t*3+2] / c;
    }
}

// ====== cooperative caps with act-finalize fused in prologue ======
template<int I, int J, int NPB>
__global__ __launch_bounds__(NPB*I*J)
void caps_coop_fin(const float* __restrict__ poseIn, const float* __restrict__ agacc,
                   const float* __restrict__ wsum, const float* __restrict__ q,
                   float* __restrict__ poseOut, float* __restrict__ actOut, int N){
    const int IJ = I*J;
    const int tid = threadIdx.x;
    const int nl  = tid / IJ;
    const int li  = tid - nl*IJ;
    const int i   = li / J;
    const int j   = li - i*J;
    const int node = blockIdx.x*NPB + nl;
    const bool on = (node < N);

    __shared__ float redA[NPB][I*J];
    __shared__ float redB[NPB][I*J];
    __shared__ float cp[NPB][I*J*4];
    __shared__ float vsh[NPB][J*4];

    float prx=0.f, pry=0.f, prz=0.f, prw=0.f, ai=0.f;
    if (on){
        float qx = q[li*4+0], qy = q[li*4+1], qz = q[li*4+2], qw = q[li*4+3];
        float qinv = 1.0f/(sqrtf(qx*qx+qy*qy+qz*qz+qw*qw)+EPS);
        qx*=qinv; qy*=qinv; qz*=qinv; qw*=qinv;
        const float* pp = &poseIn[((size_t)node*I + i)*4];
        float rx=pp[0], ry=pp[1], rz=pp[2], rw=pp[3];
        ai = sigmoidf_(agacc[(size_t)node*I + i] / (wsum[(size_t)node*I + i] + EPS));
        float tx = qw*rx + qx*rw + qy*rz - qz*ry;
        float ty = qw*ry - qx*rz + qy*rw + qz*rx;
        float tz = qw*rz + qx*ry - qy*rx + qz*rw;
        float tw = qw*rw - qx*rx - qy*ry - qz*rz;
        float pinv = 1.0f/(sqrtf(tx*tx+ty*ty+tz*tz+tw*tw)+EPS);
        prx=tx*pinv; pry=ty*pinv; prz=tz*pinv; prw=tw*pinv;
    }

    float b = 0.f, c = 0.f;
    for (int t = 0; t < 3; t++){
        redA[nl][li] = b;
        __syncthreads();
        float mb = -INFINITY;
        #pragma unroll
        for (int jj = 0; jj < J; jj++) mb = fmaxf(mb, redA[nl][i*J+jj]);
        float e = expf(b - mb);
        redB[nl][li] = e;
        __syncthreads();
        float s = 0.f;
        #pragma unroll
        for (int jj = 0; jj < J; jj++) s += redB[nl][i*J+jj];
        c = ai * e / s;
        cp[nl][li*4+0] = c*prx; cp[nl][li*4+1] = c*pry;
        cp[nl][li*4+2] = c*prz; cp[nl][li*4+3] = c*prw;
        __syncthreads();
        for (int idx = li; idx < J*4; idx += IJ){
            int jj = idx >> 2, comp = idx & 3;
            float acc = 0.f;
            #pragma unroll
            for (int ii = 0; ii < I; ii++) acc += cp[nl][(ii*J+jj)*4+comp];
            vsh[nl][idx] = acc;
        }
        __syncthreads();
        if (li < J){
            float a0=vsh[nl][li*4], a1=vsh[nl][li*4+1], a2=vsh[nl][li*4+2], a3=vsh[nl][li*4+3];
            float inv = 1.0f/(sqrtf(a0*a0+a1*a1+a2*a2+a3*a3)+EPS);
            vsh[nl][li*4]=a0*inv; vsh[nl][li*4+1]=a1*inv;
            vsh[nl][li*4+2]=a2*inv; vsh[nl][li*4+3]=a3*inv;
        }
        __syncthreads();
        if (t < 2){
            b += prx*vsh[nl][j*4] + pry*vsh[nl][j*4+1] + prz*vsh[nl][j*4+2] + prw*vsh[nl][j*4+3];
            __syncthreads();
        } else {
            redA[nl][li] = c*(prx*vsh[nl][j*4] + pry*vsh[nl][j*4+1]
                            + prz*vsh[nl][j*4+2] + prw*vsh[nl][j*4+3]);
            __syncthreads();
            if (li < J && on){
                float acc = 0.f;
                #pragma unroll
                for (int ii = 0; ii < I; ii++) acc += redA[nl][ii*J+li];
                actOut[(size_t)node*J + li] = sigmoidf_(acc);
                poseOut[((size_t)node*J+li)*4+0] = vsh[nl][li*4+0];
                poseOut[((size_t)node*J+li)*4+1] = vsh[nl][li*4+1];
                poseOut[((size_t)node*J+li)*4+2] = vsh[nl][li*4+2];
                poseOut[((size_t)node*J+li)*4+3] = vsh[nl][li*4+3];
            }
        }
    }
}

// ====== pool4 (8 nodes -> 1 voxel) + final caps<14,10>, one block ======
__global__ __launch_bounds__(192)
void pool4final_kernel(const float* __restrict__ poseIn, const float* __restrict__ actIn,
                       const float* __restrict__ q7, float* __restrict__ out){
    const int NIN = 8, JP = 14, I = 14, J = 10;
    __shared__ float mp[JP*4], ma[JP];
    __shared__ float redA[I*J], redB[I*J], cp[I*J*4], vsh[J*4];
    int t = threadIdx.x;
    if (t < JP){            // pool4: thread-per-capsule, no atomics
        float s0=0.f,s1=0.f,s2=0.f,s3=0.f,w=0.f;
        #pragma unroll
        for (int n = 0; n < NIN; n++){
            float a = actIn[n*JP + t];
            const float* pb = &poseIn[(n*JP + t)*4];
            s0 += a*pb[0]; s1 += a*pb[1]; s2 += a*pb[2]; s3 += a*pb[3];
            w += a;
        }
        float inv = 1.f/(sqrtf(s0*s0+s1*s1+s2*s2+s3*s3)+EPS);
        s0*=inv; s1*=inv; s2*=inv; s3*=inv;
        float ag = 0.f;
        #pragma unroll
        for (int n = 0; n < NIN; n++){
            float a = actIn[n*JP + t];
            const float* pb = &poseIn[(n*JP + t)*4];
            ag += a*(pb[0]*s0 + pb[1]*s1 + pb[2]*s2 + pb[3]*s3);
        }
        ma[t] = sigmoidf_(ag / (w + EPS));
        mp[t*4+0]=s0; mp[t*4+1]=s1; mp[t*4+2]=s2; mp[t*4+3]=s3;
    }
    __syncthreads();

    bool act_thr = (t < I*J);
    int li = act_thr ? t : 0;
    int i = li / J, j = li % J;
    float prx=0.f, pry=0.f, prz=0.f, prw=0.f, ai=0.f;
    if (act_thr){
        float qx=q7[li*4],qy=q7[li*4+1],qz=q7[li*4+2],qw=q7[li*4+3];
        float qinv = 1.f/(sqrtf(qx*qx+qy*qy+qz*qz+qw*qw)+EPS);
        qx*=qinv; qy*=qinv; qz*=qinv; qw*=qinv;
        float rx=mp[i*4], ry=mp[i*4+1], rz=mp[i*4+2], rw=mp[i*4+3];
        ai = ma[i];
        float tx = qw*rx + qx*rw + qy*rz - qz*ry;
        float ty = qw*ry - qx*rz + qy*rw + qz*rx;
        float tz = qw*rz + qx*ry - qy*rx + qz*rw;
        float tw = qw*rw - qx*rx - qy*ry - qz*rz;
        float pinv = 1.f/(sqrtf(tx*tx+ty*ty+tz*tz+tw*tw)+EPS);
        prx=tx*pinv; pry=ty*pinv; prz=tz*pinv; prw=tw*pinv;
    }
    float b = 0.f, c = 0.f;
    for (int it = 0; it < 3; it++){
        if (act_thr) redA[li] = b;
        __syncthreads();
        float mb = -INFINITY;
        #pragma unroll
        for (int jj = 0; jj < J; jj++) mb = fmaxf(mb, redA[i*J+jj]);
        float e = expf(b - mb);
        if (act_thr) redB[li] = e;
        __syncthreads();
        float s = 0.f;
        #pragma unroll
        for (int jj = 0; jj < J; jj++) s += redB[i*J+jj];
        c = ai * e / s;
        if (act_thr){
            cp[li*4+0]=c*prx; cp[li*4+1]=c*pry; cp[li*4+2]=c*prz; cp[li*4+3]=c*prw;
        }
        __syncthreads();
        if (act_thr){
            for (int idx = li; idx < J*4; idx += I*J){
                int jj = idx >> 2, comp = idx & 3;
                float acc = 0.f;
                #pragma unroll
                for (int ii = 0; ii < I; ii++) acc += cp[(ii*J+jj)*4+comp];
                vsh[idx] = acc;
            }
        }
        __syncthreads();
        if (act_thr && li < J){
            float a0=vsh[li*4], a1=vsh[li*4+1], a2=vsh[li*4+2], a3=vsh[li*4+3];
            float inv = 1.f/(sqrtf(a0*a0+a1*a1+a2*a2+a3*a3)+EPS);
            vsh[li*4]=a0*inv; vsh[li*4+1]=a1*inv; vsh[li*4+2]=a2*inv; vsh[li*4+3]=a3*inv;
        }
        __syncthreads();
        if (it < 2){
            b += prx*vsh[j*4] + pry*vsh[j*4+1] + prz*vsh[j*4+2] + prw*vsh[j*4+3];
            __syncthreads();
        } else {
            if (act_thr)
                redA[li] = c*(prx*vsh[j*4] + pry*vsh[j*4+1]
                            + prz*vsh[j*4+2] + prw*vsh[j*4+3]);
            __syncthreads();
            if (act_thr && li < J){
                float acc = 0.f;
                #pragma unroll
                for (int ii = 0; ii < I; ii++) acc += redA[ii*J+li];
                out[li] = sigmoidf_(acc);
            }
        }
    }
}

extern "C" void kernel_launch(void* const* d_in, const int* in_sizes, int n_in,
                              void* d_out, int out_size, void* d_ws, size_t ws_size,
                              hipStream_t stream){
    const float* x      = (const float*)d_in[0];
    const float* pos    = (const float*)d_in[1];
    const float* pseudo = (const float*)d_in[2];
    const float* Wsp    = (const float*)d_in[3];
    const float* root   = (const float*)d_in[4];
    const float* bias   = (const float*)d_in[5];
    const float* lin_w  = (const float*)d_in[6];
    const float* lin_b  = (const float*)d_in[7];
    const float* q0     = (const float*)d_in[8];
    const float* q1     = (const float*)d_in[9];
    const float* q3     = (const float*)d_in[10];
    const float* q5     = (const float*)d_in[11];
    const float* q6     = (const float*)d_in[12];
    const float* q7     = (const float*)d_in[13];
    const int*   ei     = (const int*)d_in[14];
    const int N = in_sizes[0];
    const int E = in_sizes[2] / 3;
    const int V1 = 32768;
    const int NB = (N + 255)/256;

    char* ws = (char*)d_ws;
    size_t off = 0;
    auto alloc = [&](size_t bytes)->void*{
        void* p = ws + off;
        off += (bytes + 255) & ~(size_t)255;
        return p;
    };
    unsigned* mm   = (unsigned*)alloc(8);
    int* deg       = (int*)alloc((size_t)N*sizeof(int));
    int* erank     = (int*)alloc((size_t)E*sizeof(int));
    int* eoff      = (int*)alloc((size_t)(N+1)*sizeof(int));
    int* bsum      = (int*)alloc((size_t)(NB+1)*sizeof(int));
    float4* rec4   = (float4*)alloc((size_t)E*sizeof(float4));
    int* recb      = (int*)alloc((size_t)E*sizeof(int));
    int* vhead     = (int*)alloc((size_t)V1*sizeof(int));
    int* vnxt      = (int*)alloc((size_t)N*sizeof(int));
    float* P0  = (float*)alloc((size_t)1250000*sizeof(float));
    float* P1  = (float*)alloc((size_t)1250000*sizeof(float));
    float* A0  = (float*)alloc((size_t)310000*sizeof(float));
    float* A1  = (float*)alloc((size_t)310000*sizeof(float));
    float* PB0 = (float*)alloc((size_t)100000*sizeof(float));
    float* PB1 = (float*)alloc((size_t)100000*sizeof(float));
    size_t z0 = off;                                // zeroed pool-scratch region start
    float* vs2 = (float*)alloc((size_t)512*8*4*sizeof(float));
    float* vw2 = (float*)alloc((size_t)512*8*sizeof(float));
    float* va2 = (float*)alloc((size_t)512*8*sizeof(float));
    float* vc2 = (float*)alloc((size_t)512*sizeof(float));
    float* vp2 = (float*)alloc((size_t)512*3*sizeof(float));
    float* vs3 = (float*)alloc((size_t)8*12*4*sizeof(float));
    float* vw3 = (float*)alloc((size_t)8*12*sizeof(float));
    float* va3 = (float*)alloc((size_t)8*12*sizeof(float));
    float* vc3 = (float*)alloc((size_t)8*sizeof(float));
    float* vp3 = (float*)alloc((size_t)8*3*sizeof(float));
    size_t z1 = off;
    float* pzero = (float*)(ws + z0);
    const int PZ = (int)((z1 - z0)/sizeof(float));  // zero whole region incl. padding

    // 17 dispatches (R8 structure, scan_top folded into scan_final2)
    init_kernel<<<256, 256, 0, stream>>>(mm, deg, N, vhead, V1, pzero, PZ);
    prep_kernel<<<2048, 256, 0, stream>>>(pos, N*3, mm, ei, deg, erank, E);
    scan_bsum<<<NB, 256, 0, stream>>>(deg, bsum, N);
    scan_final2<<<NB, 256, 0, stream>>>(deg, bsum, eoff, N, NB);
    edge_pack<<<(E + 255)/256, 256, 0, stream>>>(ei, pseudo, x, erank, eoff, rec4, recb, E);
    spline_node_kernel<<<(8*N + 255)/256, 256, 0, stream>>>(x, rec4, recb, eoff, Wsp,
                                                            root, bias, lin_w, lin_b, P0, A0, N);

    // caps<1,6> + caps<6,6> + pool1 list build, fused
    caps01_kernel<<<(8*N + 255)/256, 256, 0, stream>>>(P0, A0, q0, q1, P1, A1,
                                                       pos, vhead, vnxt, N, 32, mm);
    // pool1 gather + caps<6,8>, fused
    pool1caps_kernel<<<(8*V1 + 255)/256, 256, 0, stream>>>(P1, A1, pos, vhead, vnxt,
                                                           q3, P0, A0, PB0, V1);

    // pool2: 32768 -> 512 (G=8), J=8
    pool_priv1<512,8,4,2><<<128, 256, 0, stream>>>((const float4*)P0, A0, PB0,
                                                   vs2, vw2, vc2, vp2, 32768, 8, 0, mm);
    pool_m2<<<16, 256, 0, stream>>>(vs2, P1, vc2, vp2, PB1, 512, 8);
    pool_priv2<512,8><<<64, 256, 0, stream>>>((const float4*)P0, A0, PB0,
                                              (const float4*)P1, va2, 32768, 8, 0, mm);
    caps_coop_fin<8,12,2><<<256, 2*96, 0, stream>>>(P1, va2, vw2, q5, P0, A0, 512);

    // pool3: 512 -> 8 (G=2), J=12
    pool_priv1<8,12,12,1><<<16, 256, 0, stream>>>((const float4*)P0, A0, PB1,
                                                  vs3, vw3, vc3, vp3, 512, 2, 0, mm);
    pool_m2<<<1, 256, 0, stream>>>(vs3, P1, vc3, vp3, PB0, 8, 12);
    pool_priv2<8,12><<<16, 256, 0, stream>>>((const float4*)P0, A0, PB1,
                                             (const float4*)P1, va3, 512, 2, 0, mm);
    caps_coop_fin<12,14,1><<<8, 168, 0, stream>>>(P1, va3, vw3, q6, P0, A0, 8);

    // pool4 + final caps<14,10>, fused single block -> d_out
    pool4final_kernel<<<1, 192, 0, stream>>>(P0, A0, q7, (float*)d_out);
}

// Round 11
// 306.848 us; speedup vs baseline: 2.9245x; 1.0729x over previous
//
#include <hip/hip_runtime.h>
#include <math.h>

#define EPS 1e-4f

__device__ __forceinline__ float sigmoidf_(float x){ return 1.0f/(1.0f+expf(-x)); }

// ---- ordered-uint mapping for float atomic min/max ----
__device__ __forceinline__ unsigned f2u_(float f){
    unsigned u = __float_as_uint(f);
    return (u & 0x80000000u) ? ~u : (u | 0x80000000u);
}
__device__ __forceinline__ float u2f_(unsigned u){
    unsigned b = (u & 0x80000000u) ? (u & 0x7FFFFFFFu) : ~u;
    return __uint_as_float(b);
}

// ================= init: all memsets in one launch =================
__global__ void init_kernel(unsigned* __restrict__ mm, int* __restrict__ deg, int N,
                            int* __restrict__ vhead, int V,
                            float* __restrict__ pz, int PZ){
    int i = blockIdx.x*blockDim.x + threadIdx.x;
    int stride = gridDim.x*blockDim.x;
    if (i == 0){ mm[0] = 0xFFFFFFFFu; mm[1] = 0u; }
    for (int t = i; t < N; t += stride) deg[t] = 0;
    for (int t = i; t < V; t += stride) vhead[t] = -1;
    for (int t = i; t < PZ; t += stride) pz[t] = 0.f;
}

// ================= prep: minmax(pos) + edge_rank fused =================
// A/B evidence: 512 blocks = 44us (R8), 2048 blocks = 67us (R10). The 800K
// device-scope atomicAdds execute at the MEMORY-SIDE atomic unit (28MB sector
// traffic for a 200KB array); extra waves add contention, not hiding. 512 blocks
// is the measured contention-optimal point. Do not raise the grid.
__global__ void prep_kernel(const float* __restrict__ p, int n3, unsigned* mm,
                            const int* __restrict__ ei, int* __restrict__ deg,
                            int* __restrict__ rank, int E){
    int gid = blockIdx.x*blockDim.x + threadIdx.x;
    int stride = gridDim.x*blockDim.x;
    float lo = INFINITY, hi = -INFINITY;
    for (int i = gid; i < n3; i += stride){
        float v = p[i]; lo = fminf(lo, v); hi = fmaxf(hi, v);
    }
    for (int off = 32; off > 0; off >>= 1){
        lo = fminf(lo, __shfl_down(lo, off));
        hi = fmaxf(hi, __shfl_down(hi, off));
    }
    __shared__ float slo[4], shi[4];
    int wid = threadIdx.x >> 6;
    if ((threadIdx.x & 63) == 0){ slo[wid] = lo; shi[wid] = hi; }
    __syncthreads();
    if (threadIdx.x == 0){
        for (int w = 1; w < 4; w++){ lo = fminf(lo, slo[w]); hi = fmaxf(hi, shi[w]); }
        atomicMin(&mm[0], f2u_(lo));
        atomicMax(&mm[1], f2u_(hi));
    }
    for (int e = gid; e < E; e += stride)
        rank[e] = atomicAdd(&deg[ei[E + e]], 1);
}

// ================= CSR scan: per-block sums, then fused final =================
__global__ __launch_bounds__(256)
void scan_bsum(const int* __restrict__ deg, int* __restrict__ bsum, int N){
    int i = blockIdx.x*256 + threadIdx.x;
    int v = (i < N) ? deg[i] : 0;
    for (int o = 32; o > 0; o >>= 1) v += __shfl_down(v, o);
    __shared__ int ws[4];
    if ((threadIdx.x & 63) == 0) ws[threadIdx.x >> 6] = v;
    __syncthreads();
    if (threadIdx.x == 0) bsum[blockIdx.x] = ws[0] + ws[1] + ws[2] + ws[3];
}

// scan_top folded in: every block redundantly scans the <=256 raw block-sums in LDS
// (parallel, ~us) -- saves one launch+gap vs the 3-kernel scan. bsum stays unmutated.
__global__ __launch_bounds__(256)
void scan_final2(const int* __restrict__ deg, const int* __restrict__ bsum,
                 int* __restrict__ off, int N, int NB){
    __shared__ int sh[256], top[256];
    int b = blockIdx.x;
    int t = threadIdx.x;
    int bv = (t < NB) ? bsum[t] : 0;
    top[t] = bv;
    __syncthreads();
    for (int d = 1; d < 256; d <<= 1){
        int u = (t >= d) ? top[t - d] : 0;
        __syncthreads();
        top[t] += u;
        __syncthreads();
    }
    int i = b*256 + t;
    int v = (i < N) ? deg[i] : 0;
    sh[t] = v;
    __syncthreads();
    for (int d = 1; d < 256; d <<= 1){
        int u = (t >= d) ? sh[t - d] : 0;
        __syncthreads();
        sh[t] += u;
        __syncthreads();
    }
    int pre = (b == 0) ? 0 : top[b-1];
    if (i < N) off[i] = pre + sh[t] - v;                  // exclusive
    if (b == 0 && t == 0) off[N] = top[NB-1];
}

// streaming pack + atomic-free scatter: slot = off[dst] + rank[e]  (R8-proven)
__global__ void edge_pack(const int* __restrict__ ei, const float* __restrict__ pseudo,
                          const float* __restrict__ x,
                          const int* __restrict__ rank, const int* __restrict__ off,
                          float4* __restrict__ rec4, int* __restrict__ recb, int E){
    int e = blockIdx.x*blockDim.x + threadIdx.x;
    if (e >= E) return;
    float p0 = pseudo[3*e], p1 = pseudo[3*e+1], p2 = pseudo[3*e+2];
    int s = ei[e], d = ei[E + e];
    float v0 = p0*4.f, v1 = p1*4.f, v2 = p2*4.f;
    float f0 = fminf(fmaxf(floorf(v0), 0.f), 3.f);
    float f1 = fminf(fmaxf(floorf(v1), 0.f), 3.f);
    float f2 = fminf(fmaxf(floorf(v2), 0.f), 3.f);
    int slot = off[d] + rank[e];
    rec4[slot] = make_float4(v0 - f0, v1 - f1, v2 - f2, x[s]);
    recb[slot] = ((int)f0*5 + (int)f1)*5 + (int)f2;
}

__device__ __forceinline__ int voxel_id(const float* __restrict__ pos, int n, int G,
                                        float start, float size){
    int g[3];
    #pragma unroll
    for (int k = 0; k < 3; k++){
        float gg = floorf((pos[(size_t)n*3 + k] - start) / size);
        gg = fminf(fmaxf(gg, 0.f), (float)(G - 1));
        g[k] = (int)gg;
    }
    return (g[0]*G + g[1])*G + g[2];
}

__device__ __forceinline__ void pool_geom(const unsigned* mm, int G, int mode,
                                          float& start, float& size){
    float mn = u2f_(mm[0]), mx = u2f_(mm[1]);
    if (mode == 0){ start = mn; size = (mx + 0.001f - mn) / (float)G; }
    else          { start = mn - 0.5f; size = mx - mn + 1.0f; }
}

// ===== fused spline gather + node finalize: 8 lanes per node (tid = n*8+k) =====
__global__ __launch_bounds__(256)
void spline_node_kernel(const float* __restrict__ x, const float4* __restrict__ rec4,
                        const int* __restrict__ recb, const int* __restrict__ off,
                        const float* __restrict__ W,
                        const float* __restrict__ root, const float* __restrict__ bias,
                        const float* __restrict__ lin_w, const float* __restrict__ lin_b,
                        float* __restrict__ pose, float* __restrict__ act, int N){
    __shared__ float Ws[125*17];
    for (int i = threadIdx.x; i < 125*16; i += blockDim.x)
        Ws[(i >> 4)*17 + (i & 15)] = W[i];
    __syncthreads();
    int t = blockIdx.x*blockDim.x + threadIdx.x;
    int n = t >> 3;
    int k = t & 7;
    if (n >= N) return;     // group-uniform guard (all 8 lanes share n)

    int o0 = off[n], o1 = off[n+1];

    float agg[16];
    #pragma unroll
    for (int o = 0; o < 16; o++) agg[o] = 0.f;

    for (int s = o0 + k; s < o1; s += 8){
        float4 rv = rec4[s];
        int base = recb[s];
        float fr0 = rv.x, fr1 = rv.y, fr2 = rv.z, xv = rv.w;
        #pragma unroll
        for (int b = 0; b < 8; b++){
            int b0 = (b >> 2) & 1, b1 = (b >> 1) & 1, b2 = b & 1;
            float w = (b0 ? fr0 : 1.f - fr0) * (b1 ? fr1 : 1.f - fr1) * (b2 ? fr2 : 1.f - fr2);
            w *= xv;
            const float* Wr = &Ws[(base + b0*25 + b1*5 + b2)*17];
            #pragma unroll
            for (int o = 0; o < 16; o++) agg[o] += w * Wr[o];
        }
    }

    #pragma unroll
    for (int o = 0; o < 16; o++){
        agg[o] += __shfl_xor(agg[o], 1);
        agg[o] += __shfl_xor(agg[o], 2);
        agg[o] += __shfl_xor(agg[o], 4);
    }

    if (k != 0) return;

    float deg = fmaxf((float)(o1 - o0), 1.0f);
    float xs = x[n];
    float qv0 = lin_b[0], qv1 = lin_b[1], qv2 = lin_b[2], qv3 = lin_b[3];
    #pragma unroll
    for (int o = 0; o < 16; o++){
        float h = agg[o] / deg + xs * root[o] + bias[o];
        float e = (h > 0.f) ? h : expm1f(h);
        qv0 += e * lin_w[o*4 + 0];
        qv1 += e * lin_w[o*4 + 1];
        qv2 += e * lin_w[o*4 + 2];
        qv3 += e * lin_w[o*4 + 3];
    }
    float inv = 1.0f / (sqrtf(qv0*qv0 + qv1*qv1 + qv2*qv2 + qv3*qv3) + EPS);
    pose[(size_t)n*4 + 0] = qv0*inv;
    pose[(size_t)n*4 + 1] = qv1*inv;
    pose[(size_t)n*4 + 2] = qv2*inv;
    pose[(size_t)n*4 + 3] = qv3*inv;
    act[n] = xs;
}

// ====== wave-level routing core (R6-verified math, 8-lane group) ======
__device__ __forceinline__ void quat_pred(const float* qq, float px, float py, float pz,
                                          float pw, float* pr){
    float qx=qq[0], qy=qq[1], qz=qq[2], qw=qq[3];
    float tx = qw*px + qx*pw + qy*pz - qz*py;
    float ty = qw*py - qx*pz + qy*pw + qz*px;
    float tz = qw*pz + qx*py - qy*px + qz*pw;
    float tw = qw*pw - qx*px - qy*py - qz*pz;
    float inv = 1.f/(sqrtf(tx*tx+ty*ty+tz*tz+tw*tw)+EPS);
    pr[0]=tx*inv; pr[1]=ty*inv; pr[2]=tz*inv; pr[3]=tw*inv;
}

template<int I>
__device__ __forceinline__ void caps_route8(const float (*pr)[4], const float* a, bool on,
                                            float* c, float& v0, float& v1,
                                            float& v2, float& v3){
    float b[I];
    #pragma unroll
    for (int i = 0; i < I; i++) b[i] = on ? 0.f : -INFINITY;
    v0=v1=v2=v3=0.f;
    #pragma unroll
    for (int t = 0; t < 3; t++){
        #pragma unroll
        for (int i = 0; i < I; i++){
            float mb = b[i];
            mb = fmaxf(mb, __shfl_xor(mb, 1));
            mb = fmaxf(mb, __shfl_xor(mb, 2));
            mb = fmaxf(mb, __shfl_xor(mb, 4));
            float e = on ? expf(b[i] - mb) : 0.f;
            float s = e;
            s += __shfl_xor(s, 1);
            s += __shfl_xor(s, 2);
            s += __shfl_xor(s, 4);
            c[i] = a[i] * e / s;
        }
        float s0=0.f, s1=0.f, s2=0.f, s3=0.f;
        #pragma unroll
        for (int i = 0; i < I; i++){
            s0 += c[i]*pr[i][0]; s1 += c[i]*pr[i][1];
            s2 += c[i]*pr[i][2]; s3 += c[i]*pr[i][3];
        }
        float inv = 1.f/(sqrtf(s0*s0+s1*s1+s2*s2+s3*s3)+EPS);
        v0=s0*inv; v1=s1*inv; v2=s2*inv; v3=s3*inv;
        if (t < 2){
            #pragma unroll
            for (int i = 0; i < I; i++)
                b[i] += pr[i][0]*v0 + pr[i][1]*v1 + pr[i][2]*v2 + pr[i][3]*v3;
        }
    }
}

// ====== caps<1,6> + caps<6,6> + pool1 elist build, fused per node ======
__global__ __launch_bounds__(256)
void caps01_kernel(const float* __restrict__ pose0, const float* __restrict__ act0,
                   const float* __restrict__ q0, const float* __restrict__ q1,
                   float* __restrict__ poseOut, float* __restrict__ actOut,
                   const float* __restrict__ pos, int* __restrict__ vhead,
                   int* __restrict__ vnxt, int N, int G,
                   const unsigned* __restrict__ mm){
    __shared__ float qn0[6*4], qn1[36*4];
    for (int t = threadIdx.x; t < 6; t += blockDim.x){
        float qa=q0[t*4],qb=q0[t*4+1],qc=q0[t*4+2],qd=q0[t*4+3];
        float inv=1.f/(sqrtf(qa*qa+qb*qb+qc*qc+qd*qd)+EPS);
        qn0[t*4]=qa*inv; qn0[t*4+1]=qb*inv; qn0[t*4+2]=qc*inv; qn0[t*4+3]=qd*inv;
    }
    for (int t = threadIdx.x; t < 36; t += blockDim.x){
        float qa=q1[t*4],qb=q1[t*4+1],qc=q1[t*4+2],qd=q1[t*4+3];
        float inv=1.f/(sqrtf(qa*qa+qb*qb+qc*qc+qd*qd)+EPS);
        qn1[t*4]=qa*inv; qn1[t*4+1]=qb*inv; qn1[t*4+2]=qc*inv; qn1[t*4+3]=qd*inv;
    }
    __syncthreads();
    int tid = blockIdx.x*blockDim.x + threadIdx.x;
    int n = tid >> 3, j = tid & 7;
    if (n >= N) return;          // group-uniform
    bool on = (j < 6);

    // layer 0 (I=1, J=6)
    float4 p0 = *reinterpret_cast<const float4*>(&pose0[(size_t)n*4]);
    float aa0[1] = { act0[n] };
    float pr0[1][4] = {{0.f,0.f,0.f,0.f}};
    if (on) quat_pred(&qn0[j*4], p0.x, p0.y, p0.z, p0.w, pr0[0]);
    float c0[1], v0x, v0y, v0z, v0w;
    caps_route8<1>(pr0, aa0, on, c0, v0x, v0y, v0z, v0w);
    float al0 = sigmoidf_(c0[0]*(pr0[0][0]*v0x + pr0[0][1]*v0y
                                + pr0[0][2]*v0z + pr0[0][3]*v0w));

    // gather layer-0 outputs from lanes 0..5
    float pi[6][4], ai[6];
    #pragma unroll
    for (int i = 0; i < 6; i++){
        pi[i][0] = __shfl(v0x, i, 8);
        pi[i][1] = __shfl(v0y, i, 8);
        pi[i][2] = __shfl(v0z, i, 8);
        pi[i][3] = __shfl(v0w, i, 8);
        ai[i]    = __shfl(al0, i, 8);
    }

    // layer 1 (I=6, J=6)
    float pr[6][4];
    #pragma unroll
    for (int i = 0; i < 6; i++){
        pr[i][0]=pr[i][1]=pr[i][2]=pr[i][3]=0.f;
        if (on) quat_pred(&qn1[(i*6+j)*4], pi[i][0], pi[i][1], pi[i][2], pi[i][3], pr[i]);
    }
    float c1[6], v1x, v1y, v1z, v1w;
    caps_route8<6>(pr, ai, on, c1, v1x, v1y, v1z, v1w);
    if (on){
        float acc = 0.f;
        #pragma unroll
        for (int i = 0; i < 6; i++)
            acc += c1[i]*(pr[i][0]*v1x + pr[i][1]*v1y + pr[i][2]*v1z + pr[i][3]*v1w);
        actOut[(size_t)n*6 + j] = sigmoidf_(acc);
        *reinterpret_cast<float4*>(&poseOut[((size_t)n*6 + j)*4]) =
            make_float4(v1x, v1y, v1z, v1w);
    }
    if (j == 0){   // pool1 linked-list build
        float start, size; pool_geom(mm, G, 0, start, size);
        int vid = voxel_id(pos, n, G, start, size);
        vnxt[n] = atomicExch(&vhead[vid], n);
    }
}

// ====== pool1 gather + caps<6,8>, fused per voxel (8 lanes/voxel) ======
__global__ __launch_bounds__(256)
void pool1caps_kernel(const float* __restrict__ poseIn, const float* __restrict__ actIn,
                      const float* __restrict__ pos,
                      const int* __restrict__ head, const int* __restrict__ nxt,
                      const float* __restrict__ q3,
                      float* __restrict__ poseOut, float* __restrict__ actOut,
                      float* __restrict__ posOut, int V){
    __shared__ float qn[48*4];
    for (int t = threadIdx.x; t < 48; t += blockDim.x){
        float qa=q3[t*4],qb=q3[t*4+1],qc=q3[t*4+2],qd=q3[t*4+3];
        float inv=1.f/(sqrtf(qa*qa+qb*qb+qc*qc+qd*qd)+EPS);
        qn[t*4]=qa*inv; qn[t*4+1]=qb*inv; qn[t*4+2]=qc*inv; qn[t*4+3]=qd*inv;
    }
    __syncthreads();
    int tid = blockIdx.x*blockDim.x + threadIdx.x;
    int v = tid >> 3, j = tid & 7;
    if (v >= V) return;          // group-uniform
    bool onj = (j < 6);

    float s0=0.f,s1=0.f,s2=0.f,s3=0.f, w=0.f, ps0=0.f,ps1=0.f,ps2=0.f;
    int cnt = 0;
    for (int n = head[v]; n >= 0; n = nxt[n]){
        if (onj){
            float aj = actIn[(size_t)n*6 + j];
            float4 pb = *reinterpret_cast<const float4*>(&poseIn[((size_t)n*6 + j)*4]);
            s0 += aj*pb.x; s1 += aj*pb.y; s2 += aj*pb.z; s3 += aj*pb.w;
            w += aj;
        } else if (j == 6){
            ps0 += pos[(size_t)n*3+0]; ps1 += pos[(size_t)n*3+1]; ps2 += pos[(size_t)n*3+2];
        }
        cnt++;
    }
    float m0=0.f,m1=0.f,m2=0.f,m3=0.f;
    if (onj){
        float inv = 1.f/(sqrtf(s0*s0+s1*s1+s2*s2+s3*s3)+EPS);
        m0=s0*inv; m1=s1*inv; m2=s2*inv; m3=s3*inv;
    }
    float ag = 0.f;
    for (int n = head[v]; n >= 0; n = nxt[n]){
        if (onj){
            float aj = actIn[(size_t)n*6 + j];
            float4 pb = *reinterpret_cast<const float4*>(&poseIn[((size_t)n*6 + j)*4]);
            ag += aj*(pb.x*m0 + pb.y*m1 + pb.z*m2 + pb.w*m3);
        }
    }
    float actm = sigmoidf_(ag/(w+EPS));   // valid j<6
    if (j == 6){
        float c = (float)cnt + EPS;
        posOut[(size_t)v*3+0] = ps0/c;
        posOut[(size_t)v*3+1] = ps1/c;
        posOut[(size_t)v*3+2] = ps2/c;
    }

    // caps 6 -> 8 (all 8 lanes active)
    float pi[6][4], ai[6];
    #pragma unroll
    for (int i = 0; i < 6; i++){
        pi[i][0] = __shfl(m0, i, 8);
        pi[i][1] = __shfl(m1, i, 8);
        pi[i][2] = __shfl(m2, i, 8);
        pi[i][3] = __shfl(m3, i, 8);
        ai[i]    = __shfl(actm, i, 8);
    }
    float pr[6][4];
    #pragma unroll
    for (int i = 0; i < 6; i++)
        quat_pred(&qn[(i*8+j)*4], pi[i][0], pi[i][1], pi[i][2], pi[i][3], pr[i]);
    float c1[6], vx, vy, vz, vw;
    caps_route8<6>(pr, ai, true, c1, vx, vy, vz, vw);
    float acc = 0.f;
    #pragma unroll
    for (int i = 0; i < 6; i++)
        acc += c1[i]*(pr[i][0]*vx + pr[i][1]*vy + pr[i][2]*vz + pr[i][3]*vw);
    actOut[(size_t)v*8 + j] = sigmoidf_(acc);
    *reinterpret_cast<float4*>(&poseOut[((size_t)v*8 + j)*4]) = make_float4(vx, vy, vz, vw);
}

// ---------- pools 2-3: node-parallel LDS-privatized (proven R3 path) ----------
template<int V, int J, int CH, int NCHUNK>
__global__ void pool_priv1(const float4* __restrict__ poseIn, const float* __restrict__ actIn,
                           const float* __restrict__ posIn,
                           float* __restrict__ s, float* __restrict__ wsum,
                           float* __restrict__ cnt, float* __restrict__ psum,
                           int N, int G, int mode, const unsigned* __restrict__ mm){
    __shared__ float s_[V*CH*4];
    __shared__ float wsum_[V*CH];
    __shared__ float cnt_[V];
    __shared__ float psum_[V*3];
    const int chunk = blockIdx.x % NCHUNK;
    const int slice = blockIdx.x / NCHUNK;
    const int nslices = gridDim.x / NCHUNK;
    const int c0 = chunk * CH;

    for (int t = threadIdx.x; t < V*CH*4; t += blockDim.x) s_[t] = 0.f;
    for (int t = threadIdx.x; t < V*CH; t += blockDim.x) wsum_[t] = 0.f;
    if (chunk == 0){
        for (int t = threadIdx.x; t < V; t += blockDim.x) cnt_[t] = 0.f;
        for (int t = threadIdx.x; t < V*3; t += blockDim.x) psum_[t] = 0.f;
    }
    __syncthreads();

    float start, size; pool_geom(mm, G, mode, start, size);
    int per = (N + nslices - 1) / nslices;
    int n0 = slice * per, n1 = min(N, n0 + per);

    for (int n = n0 + (int)threadIdx.x; n < n1; n += blockDim.x){
        int vid = voxel_id(posIn, n, G, start, size);
        #pragma unroll
        for (int jj = 0; jj < CH; jj++){
            int j = c0 + jj;
            float aj = actIn[(size_t)n*J + j];
            float4 p = poseIn[(size_t)n*J + j];
            int b = (vid*CH + jj)*4;
            atomicAdd(&s_[b+0], aj*p.x);
            atomicAdd(&s_[b+1], aj*p.y);
            atomicAdd(&s_[b+2], aj*p.z);
            atomicAdd(&s_[b+3], aj*p.w);
            atomicAdd(&wsum_[vid*CH + jj], aj);
        }
        if (chunk == 0){
            atomicAdd(&cnt_[vid], 1.0f);
            atomicAdd(&psum_[vid*3+0], posIn[(size_t)n*3+0]);
            atomicAdd(&psum_[vid*3+1], posIn[(size_t)n*3+1]);
            atomicAdd(&psum_[vid*3+2], posIn[(size_t)n*3+2]);
        }
    }
    __syncthreads();

    for (int t = threadIdx.x; t < V*CH*4; t += blockDim.x){
        float val = s_[t];
        if (val != 0.f){
            int v = t / (CH*4), r = t % (CH*4);
            atomicAdd(&s[((size_t)v*J + c0)*4 + r], val);
        }
    }
    for (int t = threadIdx.x; t < V*CH; t += blockDim.x){
        float val = wsum_[t];
        if (val != 0.f){
            int v = t / CH, jj = t % CH;
            atomicAdd(&wsum[(size_t)v*J + c0 + jj], val);
        }
    }
    if (chunk == 0){
        for (int t = threadIdx.x; t < V; t += blockDim.x)
            if (cnt_[t] != 0.f) atomicAdd(&cnt[t], cnt_[t]);
        for (int t = threadIdx.x; t < V*3; t += blockDim.x)
            if (psum_[t] != 0.f) atomicAdd(&psum[t], psum_[t]);
    }
}

template<int V, int J>
__global__ void pool_priv2(const float4* __restrict__ poseIn, const float* __restrict__ actIn,
                           const float* __restrict__ posIn, const float4* __restrict__ m,
                           float* __restrict__ agacc,
                           int N, int G, int mode, const unsigned* __restrict__ mm){
    __shared__ float ag_[V*J];
    for (int t = threadIdx.x; t < V*J; t += blockDim.x) ag_[t] = 0.f;
    __syncthreads();
    float start, size; pool_geom(mm, G, mode, start, size);
    int nslices = gridDim.x;
    int per = (N + nslices - 1) / nslices;
    int n0 = blockIdx.x * per, n1 = min(N, n0 + per);
    for (int n = n0 + (int)threadIdx.x; n < n1; n += blockDim.x){
        int vid = voxel_id(posIn, n, G, start, size);
        #pragma unroll
        for (int j = 0; j < J; j++){
            float4 p  = poseIn[(size_t)n*J + j];
            float4 mv = m[(size_t)vid*J + j];
            float agree = p.x*mv.x + p.y*mv.y + p.z*mv.z + p.w*mv.w;
            atomicAdd(&ag_[vid*J + j], actIn[(size_t)n*J + j]*agree);
        }
    }
    __syncthreads();
    for (int t = threadIdx.x; t < V*J; t += blockDim.x)
        if (ag_[t] != 0.f) atomicAdd(&agacc[t], ag_[t]);
}

// pool_m + pos finalize in one kernel
__global__ void pool_m2(const float* __restrict__ s, float* __restrict__ m,
                        const float* __restrict__ cnt, const float* __restrict__ psum,
                        float* __restrict__ posOut, int V, int J){
    int t = blockIdx.x*blockDim.x + threadIdx.x;
    if (t < V*J){
        float a = s[(size_t)t*4], b = s[(size_t)t*4+1];
        float c = s[(size_t)t*4+2], d = s[(size_t)t*4+3];
        float inv = 1.0f / (sqrtf(a*a + b*b + c*c + d*d) + EPS);
        m[(size_t)t*4]   = a*inv;
        m[(size_t)t*4+1] = b*inv;
        m[(size_t)t*4+2] = c*inv;
        m[(size_t)t*4+3] = d*inv;
    }
    if (t < V){
        float c = cnt[t] + EPS;
        posOut[(size_t)t*3+0] = psum[(size_t)t*3+0] / c;
        posOut[(size_t)t*3+1] = psum[(size_t)t*3+1] / c;
        posOut[(size_t)t*3+2] = psum[(size_t)t*3+2] / c;
    }
}

// ====== cooperative caps with act-finalize fused in prologue ======
template<int I, int J, int NPB>
__global__ __launch_bounds__(NPB*I*J)
void caps_coop_fin(const float* __restrict__ poseIn, const float* __restrict__ agacc,
                   const float* __restrict__ wsum, const float* __restrict__ q,
                   float* __restrict__ poseOut, float* __restrict__ actOut, int N){
    const int IJ = I*J;
    const int tid = threadIdx.x;
    const int nl  = tid / IJ;
    const int li  = tid - nl*IJ;
    const int i   = li / J;
    const int j   = li - i*J;
    const int node = blockIdx.x*NPB + nl;
    const bool on = (node < N);

    __shared__ float redA[NPB][I*J];
    __shared__ float redB[NPB][I*J];
    __shared__ float cp[NPB][I*J*4];
    __shared__ float vsh[NPB][J*4];

    float prx=0.f, pry=0.f, prz=0.f, prw=0.f, ai=0.f;
    if (on){
        float qx = q[li*4+0], qy = q[li*4+1], qz = q[li*4+2], qw = q[li*4+3];
        float qinv = 1.0f/(sqrtf(qx*qx+qy*qy+qz*qz+qw*qw)+EPS);
        qx*=qinv; qy*=qinv; qz*=qinv; qw*=qinv;
        const float* pp = &poseIn[((size_t)node*I + i)*4];
        float rx=pp[0], ry=pp[1], rz=pp[2], rw=pp[3];
        ai = sigmoidf_(agacc[(size_t)node*I + i] / (wsum[(size_t)node*I + i] + EPS));
        float tx = qw*rx + qx*rw + qy*rz - qz*ry;
        float ty = qw*ry - qx*rz + qy*rw + qz*rx;
        float tz = qw*rz + qx*ry - qy*rx + qz*rw;
        float tw = qw*rw - qx*rx - qy*ry - qz*rz;
        float pinv = 1.0f/(sqrtf(tx*tx+ty*ty+tz*tz+tw*tw)+EPS);
        prx=tx*pinv; pry=ty*pinv; prz=tz*pinv; prw=tw*pinv;
    }

    float b = 0.f, c = 0.f;
    for (int t = 0; t < 3; t++){
        redA[nl][li] = b;
        __syncthreads();
        float mb = -INFINITY;
        #pragma unroll
        for (int jj = 0; jj < J; jj++) mb = fmaxf(mb, redA[nl][i*J+jj]);
        float e = expf(b - mb);
        redB[nl][li] = e;
        __syncthreads();
        float s = 0.f;
        #pragma unroll
        for (int jj = 0; jj < J; jj++) s += redB[nl][i*J+jj];
        c = ai * e / s;
        cp[nl][li*4+0] = c*prx; cp[nl][li*4+1] = c*pry;
        cp[nl][li*4+2] = c*prz; cp[nl][li*4+3] = c*prw;
        __syncthreads();
        for (int idx = li; idx < J*4; idx += IJ){
            int jj = idx >> 2, comp = idx & 3;
            float acc = 0.f;
            #pragma unroll
            for (int ii = 0; ii < I; ii++) acc += cp[nl][(ii*J+jj)*4+comp];
            vsh[nl][idx] = acc;
        }
        __syncthreads();
        if (li < J){
            float a0=vsh[nl][li*4], a1=vsh[nl][li*4+1], a2=vsh[nl][li*4+2], a3=vsh[nl][li*4+3];
            float inv = 1.0f/(sqrtf(a0*a0+a1*a1+a2*a2+a3*a3)+EPS);
            vsh[nl][li*4]=a0*inv; vsh[nl][li*4+1]=a1*inv;
            vsh[nl][li*4+2]=a2*inv; vsh[nl][li*4+3]=a3*inv;
        }
        __syncthreads();
        if (t < 2){
            b += prx*vsh[nl][j*4] + pry*vsh[nl][j*4+1] + prz*vsh[nl][j*4+2] + prw*vsh[nl][j*4+3];
            __syncthreads();
        } else {
            redA[nl][li] = c*(prx*vsh[nl][j*4] + pry*vsh[nl][j*4+1]
                            + prz*vsh[nl][j*4+2] + prw*vsh[nl][j*4+3]);
            __syncthreads();
            if (li < J && on){
                float acc = 0.f;
                #pragma unroll
                for (int ii = 0; ii < I; ii++) acc += redA[nl][ii*J+li];
                actOut[(size_t)node*J + li] = sigmoidf_(acc);
                poseOut[((size_t)node*J+li)*4+0] = vsh[nl][li*4+0];
                poseOut[((size_t)node*J+li)*4+1] = vsh[nl][li*4+1];
                poseOut[((size_t)node*J+li)*4+2] = vsh[nl][li*4+2];
                poseOut[((size_t)node*J+li)*4+3] = vsh[nl][li*4+3];
            }
        }
    }
}

// ====== pool4 (8 nodes -> 1 voxel) + final caps<14,10>, one block ======
__global__ __launch_bounds__(192)
void pool4final_kernel(const float* __restrict__ poseIn, const float* __restrict__ actIn,
                       const float* __restrict__ q7, float* __restrict__ out){
    const int NIN = 8, JP = 14, I = 14, J = 10;
    __shared__ float mp[JP*4], ma[JP];
    __shared__ float redA[I*J], redB[I*J], cp[I*J*4], vsh[J*4];
    int t = threadIdx.x;
    if (t < JP){            // pool4: thread-per-capsule, no atomics
        float s0=0.f,s1=0.f,s2=0.f,s3=0.f,w=0.f;
        #pragma unroll
        for (int n = 0; n < NIN; n++){
            float a = actIn[n*JP + t];
            const float* pb = &poseIn[(n*JP + t)*4];
            s0 += a*pb[0]; s1 += a*pb[1]; s2 += a*pb[2]; s3 += a*pb[3];
            w += a;
        }
        float inv = 1.f/(sqrtf(s0*s0+s1*s1+s2*s2+s3*s3)+EPS);
        s0*=inv; s1*=inv; s2*=inv; s3*=inv;
        float ag = 0.f;
        #pragma unroll
        for (int n = 0; n < NIN; n++){
            float a = actIn[n*JP + t];
            const float* pb = &poseIn[(n*JP + t)*4];
            ag += a*(pb[0]*s0 + pb[1]*s1 + pb[2]*s2 + pb[3]*s3);
        }
        ma[t] = sigmoidf_(ag / (w + EPS));
        mp[t*4+0]=s0; mp[t*4+1]=s1; mp[t*4+2]=s2; mp[t*4+3]=s3;
    }
    __syncthreads();

    bool act_thr = (t < I*J);
    int li = act_thr ? t : 0;
    int i = li / J, j = li % J;
    float prx=0.f, pry=0.f, prz=0.f, prw=0.f, ai=0.f;
    if (act_thr){
        float qx=q7[li*4],qy=q7[li*4+1],qz=q7[li*4+2],qw=q7[li*4+3];
        float qinv = 1.f/(sqrtf(qx*qx+qy*qy+qz*qz+qw*qw)+EPS);
        qx*=qinv; qy*=qinv; qz*=qinv; qw*=qinv;
        float rx=mp[i*4], ry=mp[i*4+1], rz=mp[i*4+2], rw=mp[i*4+3];
        ai = ma[i];
        float tx = qw*rx + qx*rw + qy*rz - qz*ry;
        float ty = qw*ry - qx*rz + qy*rw + qz*rx;
        float tz = qw*rz + qx*ry - qy*rx + qz*rw;
        float tw = qw*rw - qx*rx - qy*ry - qz*rz;
        float pinv = 1.f/(sqrtf(tx*tx+ty*ty+tz*tz+tw*tw)+EPS);
        prx=tx*pinv; pry=ty*pinv; prz=tz*pinv; prw=tw*pinv;
    }
    float b = 0.f, c = 0.f;
    for (int it = 0; it < 3; it++){
        if (act_thr) redA[li] = b;
        __syncthreads();
        float mb = -INFINITY;
        #pragma unroll
        for (int jj = 0; jj < J; jj++) mb = fmaxf(mb, redA[i*J+jj]);
        float e = expf(b - mb);
        if (act_thr) redB[li] = e;
        __syncthreads();
        float s = 0.f;
        #pragma unroll
        for (int jj = 0; jj < J; jj++) s += redB[i*J+jj];
        c = ai * e / s;
        if (act_thr){
            cp[li*4+0]=c*prx; cp[li*4+1]=c*pry; cp[li*4+2]=c*prz; cp[li*4+3]=c*prw;
        }
        __syncthreads();
        if (act_thr){
            for (int idx = li; idx < J*4; idx += I*J){
                int jj = idx >> 2, comp = idx & 3;
                float acc = 0.f;
                #pragma unroll
                for (int ii = 0; ii < I; ii++) acc += cp[(ii*J+jj)*4+comp];
                vsh[idx] = acc;
            }
        }
        __syncthreads();
        if (act_thr && li < J){
            float a0=vsh[li*4], a1=vsh[li*4+1], a2=vsh[li*4+2], a3=vsh[li*4+3];
            float inv = 1.f/(sqrtf(a0*a0+a1*a1+a2*a2+a3*a3)+EPS);
            vsh[li*4]=a0*inv; vsh[li*4+1]=a1*inv; vsh[li*4+2]=a2*inv; vsh[li*4+3]=a3*inv;
        }
        __syncthreads();
        if (it < 2){
            b += prx*vsh[j*4] + pry*vsh[j*4+1] + prz*vsh[j*4+2] + prw*vsh[j*4+3];
            __syncthreads();
        } else {
            if (act_thr)
                redA[li] = c*(prx*vsh[j*4] + pry*vsh[j*4+1]
                            + prz*vsh[j*4+2] + prw*vsh[j*4+3]);
            __syncthreads();
            if (act_thr && li < J){
                float acc = 0.f;
                #pragma unroll
                for (int ii = 0; ii < I; ii++) acc += redA[ii*J+li];
                out[li] = sigmoidf_(acc);
            }
        }
    }
}

extern "C" void kernel_launch(void* const* d_in, const int* in_sizes, int n_in,
                              void* d_out, int out_size, void* d_ws, size_t ws_size,
                              hipStream_t stream){
    const float* x      = (const float*)d_in[0];
    const float* pos    = (const float*)d_in[1];
    const float* pseudo = (const float*)d_in[2];
    const float* Wsp    = (const float*)d_in[3];
    const float* root   = (const float*)d_in[4];
    const float* bias   = (const float*)d_in[5];
    const float* lin_w  = (const float*)d_in[6];
    const float* lin_b  = (const float*)d_in[7];
    const float* q0     = (const float*)d_in[8];
    const float* q1     = (const float*)d_in[9];
    const float* q3     = (const float*)d_in[10];
    const float* q5     = (const float*)d_in[11];
    const float* q6     = (const float*)d_in[12];
    const float* q7     = (const float*)d_in[13];
    const int*   ei     = (const int*)d_in[14];
    const int N = in_sizes[0];
    const int E = in_sizes[2] / 3;
    const int V1 = 32768;
    const int NB = (N + 255)/256;

    char* ws = (char*)d_ws;
    size_t off = 0;
    auto alloc = [&](size_t bytes)->void*{
        void* p = ws + off;
        off += (bytes + 255) & ~(size_t)255;
        return p;
    };
    unsigned* mm   = (unsigned*)alloc(8);
    int* deg       = (int*)alloc((size_t)N*sizeof(int));
    int* erank     = (int*)alloc((size_t)E*sizeof(int));
    int* eoff      = (int*)alloc((size_t)(N+1)*sizeof(int));
    int* bsum      = (int*)alloc((size_t)(NB+1)*sizeof(int));
    float4* rec4   = (float4*)alloc((size_t)E*sizeof(float4));
    int* recb      = (int*)alloc((size_t)E*sizeof(int));
    int* vhead     = (int*)alloc((size_t)V1*sizeof(int));
    int* vnxt      = (int*)alloc((size_t)N*sizeof(int));
    float* P0  = (float*)alloc((size_t)1250000*sizeof(float));
    float* P1  = (float*)alloc((size_t)1250000*sizeof(float));
    float* A0  = (float*)alloc((size_t)310000*sizeof(float));
    float* A1  = (float*)alloc((size_t)310000*sizeof(float));
    float* PB0 = (float*)alloc((size_t)100000*sizeof(float));
    float* PB1 = (float*)alloc((size_t)100000*sizeof(float));
    size_t z0 = off;                                // zeroed pool-scratch region start
    float* vs2 = (float*)alloc((size_t)512*8*4*sizeof(float));
    float* vw2 = (float*)alloc((size_t)512*8*sizeof(float));
    float* va2 = (float*)alloc((size_t)512*8*sizeof(float));
    float* vc2 = (float*)alloc((size_t)512*sizeof(float));
    float* vp2 = (float*)alloc((size_t)512*3*sizeof(float));
    float* vs3 = (float*)alloc((size_t)8*12*4*sizeof(float));
    float* vw3 = (float*)alloc((size_t)8*12*sizeof(float));
    float* va3 = (float*)alloc((size_t)8*12*sizeof(float));
    float* vc3 = (float*)alloc((size_t)8*sizeof(float));
    float* vp3 = (float*)alloc((size_t)8*3*sizeof(float));
    size_t z1 = off;
    float* pzero = (float*)(ws + z0);
    const int PZ = (int)((z1 - z0)/sizeof(float));  // zero whole region incl. padding

    // 17 dispatches; prep at its measured contention-optimal 512 blocks.
    init_kernel<<<256, 256, 0, stream>>>(mm, deg, N, vhead, V1, pzero, PZ);
    prep_kernel<<<512, 256, 0, stream>>>(pos, N*3, mm, ei, deg, erank, E);
    scan_bsum<<<NB, 256, 0, stream>>>(deg, bsum, N);
    scan_final2<<<NB, 256, 0, stream>>>(deg, bsum, eoff, N, NB);
    edge_pack<<<(E + 255)/256, 256, 0, stream>>>(ei, pseudo, x, erank, eoff, rec4, recb, E);
    spline_node_kernel<<<(8*N + 255)/256, 256, 0, stream>>>(x, rec4, recb, eoff, Wsp,
                                                            root, bias, lin_w, lin_b, P0, A0, N);

    // caps<1,6> + caps<6,6> + pool1 list build, fused
    caps01_kernel<<<(8*N + 255)/256, 256, 0, stream>>>(P0, A0, q0, q1, P1, A1,
                                                       pos, vhead, vnxt, N, 32, mm);
    // pool1 gather + caps<6,8>, fused
    pool1caps_kernel<<<(8*V1 + 255)/256, 256, 0, stream>>>(P1, A1, pos, vhead, vnxt,
                                                           q3, P0, A0, PB0, V1);

    // pool2: 32768 -> 512 (G=8), J=8
    pool_priv1<512,8,4,2><<<128, 256, 0, stream>>>((const float4*)P0, A0, PB0,
                                                   vs2, vw2, vc2, vp2, 32768, 8, 0, mm);
    pool_m2<<<16, 256, 0, stream>>>(vs2, P1, vc2, vp2, PB1, 512, 8);
    pool_priv2<512,8><<<64, 256, 0, stream>>>((const float4*)P0, A0, PB0,
                                              (const float4*)P1, va2, 32768, 8, 0, mm);
    caps_coop_fin<8,12,2><<<256, 2*96, 0, stream>>>(P1, va2, vw2, q5, P0, A0, 512);

    // pool3: 512 -> 8 (G=2), J=12
    pool_priv1<8,12,12,1><<<16, 256, 0, stream>>>((const float4*)P0, A0, PB1,
                                                  vs3, vw3, vc3, vp3, 512, 2, 0, mm);
    pool_m2<<<1, 256, 0, stream>>>(vs3, P1, vc3, vp3, PB0, 8, 12);
    pool_priv2<8,12><<<16, 256, 0, stream>>>((const float4*)P0, A0, PB1,
                                             (const float4*)P1, va3, 512, 2, 0, mm);
    caps_coop_fin<12,14,1><<<8, 168, 0, stream>>>(P1, va3, vw3, q6, P0, A0, 8);

    // pool4 + final caps<14,10>, fused single block -> d_out
    pool4final_kernel<<<1, 192, 0, stream>>>(P0, A0, q7, (float*)d_out);
}

// Round 12
// 302.891 us; speedup vs baseline: 2.9627x; 1.0131x over previous
//
#include <hip/hip_runtime.h>
#include <math.h>

#define EPS 1e-4f

__device__ __forceinline__ float sigmoidf_(float x){ return 1.0f/(1.0f+expf(-x)); }

// ---- ordered-uint mapping for float atomic min/max ----
__device__ __forceinline__ unsigned f2u_(float f){
    unsigned u = __float_as_uint(f);
    return (u & 0x80000000u) ? ~u : (u | 0x80000000u);
}
__device__ __forceinline__ float u2f_(unsigned u){
    unsigned b = (u & 0x80000000u) ? (u & 0x7FFFFFFFu) : ~u;
    return __uint_as_float(b);
}

// ================= init: all memsets in one launch =================
__global__ void init_kernel(unsigned* __restrict__ mm, int* __restrict__ deg, int N,
                            int* __restrict__ vhead, int V,
                            float* __restrict__ pz, int PZ){
    int i = blockIdx.x*blockDim.x + threadIdx.x;
    int stride = gridDim.x*blockDim.x;
    if (i == 0){ mm[0] = 0xFFFFFFFFu; mm[1] = 0u; }
    for (int t = i; t < N; t += stride) deg[t] = 0;
    for (int t = i; t < V; t += stride) vhead[t] = -1;
    for (int t = i; t < PZ; t += stride) pz[t] = 0.f;
}

// ================= prep: minmax(pos) + edge_rank fused =================
// A/B evidence: 512 blocks = 44us (R8/R11), 2048 blocks = 67us (R10). The 800K
// device-scope atomicAdds execute at the MEMORY-SIDE atomic unit (28MB sector
// traffic for a 200KB array); extra waves add contention. 512 = optimal.
__global__ void prep_kernel(const float* __restrict__ p, int n3, unsigned* mm,
                            const int* __restrict__ ei, int* __restrict__ deg,
                            int* __restrict__ rank, int E){
    int gid = blockIdx.x*blockDim.x + threadIdx.x;
    int stride = gridDim.x*blockDim.x;
    float lo = INFINITY, hi = -INFINITY;
    for (int i = gid; i < n3; i += stride){
        float v = p[i]; lo = fminf(lo, v); hi = fmaxf(hi, v);
    }
    for (int off = 32; off > 0; off >>= 1){
        lo = fminf(lo, __shfl_down(lo, off));
        hi = fmaxf(hi, __shfl_down(hi, off));
    }
    __shared__ float slo[4], shi[4];
    int wid = threadIdx.x >> 6;
    if ((threadIdx.x & 63) == 0){ slo[wid] = lo; shi[wid] = hi; }
    __syncthreads();
    if (threadIdx.x == 0){
        for (int w = 1; w < 4; w++){ lo = fminf(lo, slo[w]); hi = fmaxf(hi, shi[w]); }
        atomicMin(&mm[0], f2u_(lo));
        atomicMax(&mm[1], f2u_(hi));
    }
    for (int e = gid; e < E; e += stride)
        rank[e] = atomicAdd(&deg[ei[E + e]], 1);
}

// ================= CSR scan: per-block sums, then fused final =================
__global__ __launch_bounds__(256)
void scan_bsum(const int* __restrict__ deg, int* __restrict__ bsum, int N){
    int i = blockIdx.x*256 + threadIdx.x;
    int v = (i < N) ? deg[i] : 0;
    for (int o = 32; o > 0; o >>= 1) v += __shfl_down(v, o);
    __shared__ int ws[4];
    if ((threadIdx.x & 63) == 0) ws[threadIdx.x >> 6] = v;
    __syncthreads();
    if (threadIdx.x == 0) bsum[blockIdx.x] = ws[0] + ws[1] + ws[2] + ws[3];
}

__global__ __launch_bounds__(256)
void scan_final2(const int* __restrict__ deg, const int* __restrict__ bsum,
                 int* __restrict__ off, int N, int NB){
    __shared__ int sh[256], top[256];
    int b = blockIdx.x;
    int t = threadIdx.x;
    int bv = (t < NB) ? bsum[t] : 0;
    top[t] = bv;
    __syncthreads();
    for (int d = 1; d < 256; d <<= 1){
        int u = (t >= d) ? top[t - d] : 0;
        __syncthreads();
        top[t] += u;
        __syncthreads();
    }
    int i = b*256 + t;
    int v = (i < N) ? deg[i] : 0;
    sh[t] = v;
    __syncthreads();
    for (int d = 1; d < 256; d <<= 1){
        int u = (t >= d) ? sh[t - d] : 0;
        __syncthreads();
        sh[t] += u;
        __syncthreads();
    }
    int pre = (b == 0) ? 0 : top[b-1];
    if (i < N) off[i] = pre + sh[t] - v;                  // exclusive
    if (b == 0 && t == 0) off[N] = top[NB-1];
}

// streaming pack + atomic-free scatter: slot = off[dst] + rank[e]
__global__ void edge_pack(const int* __restrict__ ei, const float* __restrict__ pseudo,
                          const float* __restrict__ x,
                          const int* __restrict__ rank, const int* __restrict__ off,
                          float4* __restrict__ rec4, int* __restrict__ recb, int E){
    int e = blockIdx.x*blockDim.x + threadIdx.x;
    if (e >= E) return;
    float p0 = pseudo[3*e], p1 = pseudo[3*e+1], p2 = pseudo[3*e+2];
    int s = ei[e], d = ei[E + e];
    float v0 = p0*4.f, v1 = p1*4.f, v2 = p2*4.f;
    float f0 = fminf(fmaxf(floorf(v0), 0.f), 3.f);
    float f1 = fminf(fmaxf(floorf(v1), 0.f), 3.f);
    float f2 = fminf(fmaxf(floorf(v2), 0.f), 3.f);
    int slot = off[d] + rank[e];
    rec4[slot] = make_float4(v0 - f0, v1 - f1, v2 - f2, x[s]);
    recb[slot] = ((int)f0*5 + (int)f1)*5 + (int)f2;
}

__device__ __forceinline__ int voxel_id(const float* __restrict__ pos, int n, int G,
                                        float start, float size){
    int g[3];
    #pragma unroll
    for (int k = 0; k < 3; k++){
        float gg = floorf((pos[(size_t)n*3 + k] - start) / size);
        gg = fminf(fmaxf(gg, 0.f), (float)(G - 1));
        g[k] = (int)gg;
    }
    return (g[0]*G + g[1])*G + g[2];
}

// voxel id with pos computed inline from (psum, cnt): pos = psum/(cnt+EPS),
// bit-identical to the old pool_m2 store + load round-trip.
__device__ __forceinline__ int voxel_id_pc(const float* __restrict__ psum,
                                           const float* __restrict__ cnt, int n, int G,
                                           float start, float size){
    float c = cnt[n] + EPS;
    int g[3];
    #pragma unroll
    for (int k = 0; k < 3; k++){
        float pv = psum[(size_t)n*3 + k] / c;
        float gg = floorf((pv - start) / size);
        gg = fminf(fmaxf(gg, 0.f), (float)(G - 1));
        g[k] = (int)gg;
    }
    return (g[0]*G + g[1])*G + g[2];
}

__device__ __forceinline__ void pool_geom(const unsigned* mm, int G, int mode,
                                          float& start, float& size){
    float mn = u2f_(mm[0]), mx = u2f_(mm[1]);
    if (mode == 0){ start = mn; size = (mx + 0.001f - mn) / (float)G; }
    else          { start = mn - 0.5f; size = mx - mn + 1.0f; }
}

// ===== fused spline gather + node finalize: 8 lanes per node (tid = n*8+k) =====
__global__ __launch_bounds__(256)
void spline_node_kernel(const float* __restrict__ x, const float4* __restrict__ rec4,
                        const int* __restrict__ recb, const int* __restrict__ off,
                        const float* __restrict__ W,
                        const float* __restrict__ root, const float* __restrict__ bias,
                        const float* __restrict__ lin_w, const float* __restrict__ lin_b,
                        float* __restrict__ pose, float* __restrict__ act, int N){
    __shared__ float Ws[125*17];
    for (int i = threadIdx.x; i < 125*16; i += blockDim.x)
        Ws[(i >> 4)*17 + (i & 15)] = W[i];
    __syncthreads();
    int t = blockIdx.x*blockDim.x + threadIdx.x;
    int n = t >> 3;
    int k = t & 7;
    if (n >= N) return;     // group-uniform guard (all 8 lanes share n)

    int o0 = off[n], o1 = off[n+1];

    float agg[16];
    #pragma unroll
    for (int o = 0; o < 16; o++) agg[o] = 0.f;

    for (int s = o0 + k; s < o1; s += 8){
        float4 rv = rec4[s];
        int base = recb[s];
        float fr0 = rv.x, fr1 = rv.y, fr2 = rv.z, xv = rv.w;
        #pragma unroll
        for (int b = 0; b < 8; b++){
            int b0 = (b >> 2) & 1, b1 = (b >> 1) & 1, b2 = b & 1;
            float w = (b0 ? fr0 : 1.f - fr0) * (b1 ? fr1 : 1.f - fr1) * (b2 ? fr2 : 1.f - fr2);
            w *= xv;
            const float* Wr = &Ws[(base + b0*25 + b1*5 + b2)*17];
            #pragma unroll
            for (int o = 0; o < 16; o++) agg[o] += w * Wr[o];
        }
    }

    #pragma unroll
    for (int o = 0; o < 16; o++){
        agg[o] += __shfl_xor(agg[o], 1);
        agg[o] += __shfl_xor(agg[o], 2);
        agg[o] += __shfl_xor(agg[o], 4);
    }

    if (k != 0) return;

    float deg = fmaxf((float)(o1 - o0), 1.0f);
    float xs = x[n];
    float qv0 = lin_b[0], qv1 = lin_b[1], qv2 = lin_b[2], qv3 = lin_b[3];
    #pragma unroll
    for (int o = 0; o < 16; o++){
        float h = agg[o] / deg + xs * root[o] + bias[o];
        float e = (h > 0.f) ? h : expm1f(h);
        qv0 += e * lin_w[o*4 + 0];
        qv1 += e * lin_w[o*4 + 1];
        qv2 += e * lin_w[o*4 + 2];
        qv3 += e * lin_w[o*4 + 3];
    }
    float inv = 1.0f / (sqrtf(qv0*qv0 + qv1*qv1 + qv2*qv2 + qv3*qv3) + EPS);
    pose[(size_t)n*4 + 0] = qv0*inv;
    pose[(size_t)n*4 + 1] = qv1*inv;
    pose[(size_t)n*4 + 2] = qv2*inv;
    pose[(size_t)n*4 + 3] = qv3*inv;
    act[n] = xs;
}

// ====== wave-level routing core (R6-verified math, 8-lane group) ======
__device__ __forceinline__ void quat_pred(const float* qq, float px, float py, float pz,
                                          float pw, float* pr){
    float qx=qq[0], qy=qq[1], qz=qq[2], qw=qq[3];
    float tx = qw*px + qx*pw + qy*pz - qz*py;
    float ty = qw*py - qx*pz + qy*pw + qz*px;
    float tz = qw*pz + qx*py - qy*px + qz*pw;
    float tw = qw*pw - qx*px - qy*py - qz*pz;
    float inv = 1.f/(sqrtf(tx*tx+ty*ty+tz*tz+tw*tw)+EPS);
    pr[0]=tx*inv; pr[1]=ty*inv; pr[2]=tz*inv; pr[3]=tw*inv;
}

template<int I>
__device__ __forceinline__ void caps_route8(const float (*pr)[4], const float* a, bool on,
                                            float* c, float& v0, float& v1,
                                            float& v2, float& v3){
    float b[I];
    #pragma unroll
    for (int i = 0; i < I; i++) b[i] = on ? 0.f : -INFINITY;
    v0=v1=v2=v3=0.f;
    #pragma unroll
    for (int t = 0; t < 3; t++){
        #pragma unroll
        for (int i = 0; i < I; i++){
            float mb = b[i];
            mb = fmaxf(mb, __shfl_xor(mb, 1));
            mb = fmaxf(mb, __shfl_xor(mb, 2));
            mb = fmaxf(mb, __shfl_xor(mb, 4));
            float e = on ? expf(b[i] - mb) : 0.f;
            float s = e;
            s += __shfl_xor(s, 1);
            s += __shfl_xor(s, 2);
            s += __shfl_xor(s, 4);
            c[i] = a[i] * e / s;
        }
        float s0=0.f, s1=0.f, s2=0.f, s3=0.f;
        #pragma unroll
        for (int i = 0; i < I; i++){
            s0 += c[i]*pr[i][0]; s1 += c[i]*pr[i][1];
            s2 += c[i]*pr[i][2]; s3 += c[i]*pr[i][3];
        }
        float inv = 1.f/(sqrtf(s0*s0+s1*s1+s2*s2+s3*s3)+EPS);
        v0=s0*inv; v1=s1*inv; v2=s2*inv; v3=s3*inv;
        if (t < 2){
            #pragma unroll
            for (int i = 0; i < I; i++)
                b[i] += pr[i][0]*v0 + pr[i][1]*v1 + pr[i][2]*v2 + pr[i][3]*v3;
        }
    }
}

// ====== caps<1,6> + caps<6,6> + pool1 elist build, fused per node ======
__global__ __launch_bounds__(256)
void caps01_kernel(const float* __restrict__ pose0, const float* __restrict__ act0,
                   const float* __restrict__ q0, const float* __restrict__ q1,
                   float* __restrict__ poseOut, float* __restrict__ actOut,
                   const float* __restrict__ pos, int* __restrict__ vhead,
                   int* __restrict__ vnxt, int N, int G,
                   const unsigned* __restrict__ mm){
    __shared__ float qn0[6*4], qn1[36*4];
    for (int t = threadIdx.x; t < 6; t += blockDim.x){
        float qa=q0[t*4],qb=q0[t*4+1],qc=q0[t*4+2],qd=q0[t*4+3];
        float inv=1.f/(sqrtf(qa*qa+qb*qb+qc*qc+qd*qd)+EPS);
        qn0[t*4]=qa*inv; qn0[t*4+1]=qb*inv; qn0[t*4+2]=qc*inv; qn0[t*4+3]=qd*inv;
    }
    for (int t = threadIdx.x; t < 36; t += blockDim.x){
        float qa=q1[t*4],qb=q1[t*4+1],qc=q1[t*4+2],qd=q1[t*4+3];
        float inv=1.f/(sqrtf(qa*qa+qb*qb+qc*qc+qd*qd)+EPS);
        qn1[t*4]=qa*inv; qn1[t*4+1]=qb*inv; qn1[t*4+2]=qc*inv; qn1[t*4+3]=qd*inv;
    }
    __syncthreads();
    int tid = blockIdx.x*blockDim.x + threadIdx.x;
    int n = tid >> 3, j = tid & 7;
    if (n >= N) return;          // group-uniform
    bool on = (j < 6);

    // layer 0 (I=1, J=6)
    float4 p0 = *reinterpret_cast<const float4*>(&pose0[(size_t)n*4]);
    float aa0[1] = { act0[n] };
    float pr0[1][4] = {{0.f,0.f,0.f,0.f}};
    if (on) quat_pred(&qn0[j*4], p0.x, p0.y, p0.z, p0.w, pr0[0]);
    float c0[1], v0x, v0y, v0z, v0w;
    caps_route8<1>(pr0, aa0, on, c0, v0x, v0y, v0z, v0w);
    float al0 = sigmoidf_(c0[0]*(pr0[0][0]*v0x + pr0[0][1]*v0y
                                + pr0[0][2]*v0z + pr0[0][3]*v0w));

    // gather layer-0 outputs from lanes 0..5
    float pi[6][4], ai[6];
    #pragma unroll
    for (int i = 0; i < 6; i++){
        pi[i][0] = __shfl(v0x, i, 8);
        pi[i][1] = __shfl(v0y, i, 8);
        pi[i][2] = __shfl(v0z, i, 8);
        pi[i][3] = __shfl(v0w, i, 8);
        ai[i]    = __shfl(al0, i, 8);
    }

    // layer 1 (I=6, J=6)
    float pr[6][4];
    #pragma unroll
    for (int i = 0; i < 6; i++){
        pr[i][0]=pr[i][1]=pr[i][2]=pr[i][3]=0.f;
        if (on) quat_pred(&qn1[(i*6+j)*4], pi[i][0], pi[i][1], pi[i][2], pi[i][3], pr[i]);
    }
    float c1[6], v1x, v1y, v1z, v1w;
    caps_route8<6>(pr, ai, on, c1, v1x, v1y, v1z, v1w);
    if (on){
        float acc = 0.f;
        #pragma unroll
        for (int i = 0; i < 6; i++)
            acc += c1[i]*(pr[i][0]*v1x + pr[i][1]*v1y + pr[i][2]*v1z + pr[i][3]*v1w);
        actOut[(size_t)n*6 + j] = sigmoidf_(acc);
        *reinterpret_cast<float4*>(&poseOut[((size_t)n*6 + j)*4]) =
            make_float4(v1x, v1y, v1z, v1w);
    }
    if (j == 0){   // pool1 linked-list build
        float start, size; pool_geom(mm, G, 0, start, size);
        int vid = voxel_id(pos, n, G, start, size);
        vnxt[n] = atomicExch(&vhead[vid], n);
    }
}

// ====== pool1 gather + caps<6,8>, fused per voxel (8 lanes/voxel) ======
__global__ __launch_bounds__(256)
void pool1caps_kernel(const float* __restrict__ poseIn, const float* __restrict__ actIn,
                      const float* __restrict__ pos,
                      const int* __restrict__ head, const int* __restrict__ nxt,
                      const float* __restrict__ q3,
                      float* __restrict__ poseOut, float* __restrict__ actOut,
                      float* __restrict__ posOut, int V){
    __shared__ float qn[48*4];
    for (int t = threadIdx.x; t < 48; t += blockDim.x){
        float qa=q3[t*4],qb=q3[t*4+1],qc=q3[t*4+2],qd=q3[t*4+3];
        float inv=1.f/(sqrtf(qa*qa+qb*qb+qc*qc+qd*qd)+EPS);
        qn[t*4]=qa*inv; qn[t*4+1]=qb*inv; qn[t*4+2]=qc*inv; qn[t*4+3]=qd*inv;
    }
    __syncthreads();
    int tid = blockIdx.x*blockDim.x + threadIdx.x;
    int v = tid >> 3, j = tid & 7;
    if (v >= V) return;          // group-uniform
    bool onj = (j < 6);

    float s0=0.f,s1=0.f,s2=0.f,s3=0.f, w=0.f, ps0=0.f,ps1=0.f,ps2=0.f;
    int cnt = 0;
    for (int n = head[v]; n >= 0; n = nxt[n]){
        if (onj){
            float aj = actIn[(size_t)n*6 + j];
            float4 pb = *reinterpret_cast<const float4*>(&poseIn[((size_t)n*6 + j)*4]);
            s0 += aj*pb.x; s1 += aj*pb.y; s2 += aj*pb.z; s3 += aj*pb.w;
            w += aj;
        } else if (j == 6){
            ps0 += pos[(size_t)n*3+0]; ps1 += pos[(size_t)n*3+1]; ps2 += pos[(size_t)n*3+2];
        }
        cnt++;
    }
    float m0=0.f,m1=0.f,m2=0.f,m3=0.f;
    if (onj){
        float inv = 1.f/(sqrtf(s0*s0+s1*s1+s2*s2+s3*s3)+EPS);
        m0=s0*inv; m1=s1*inv; m2=s2*inv; m3=s3*inv;
    }
    float ag = 0.f;
    for (int n = head[v]; n >= 0; n = nxt[n]){
        if (onj){
            float aj = actIn[(size_t)n*6 + j];
            float4 pb = *reinterpret_cast<const float4*>(&poseIn[((size_t)n*6 + j)*4]);
            ag += aj*(pb.x*m0 + pb.y*m1 + pb.z*m2 + pb.w*m3);
        }
    }
    float actm = sigmoidf_(ag/(w+EPS));   // valid j<6
    if (j == 6){
        float c = (float)cnt + EPS;
        posOut[(size_t)v*3+0] = ps0/c;
        posOut[(size_t)v*3+1] = ps1/c;
        posOut[(size_t)v*3+2] = ps2/c;
    }

    // caps 6 -> 8 (all 8 lanes active)
    float pi[6][4], ai[6];
    #pragma unroll
    for (int i = 0; i < 6; i++){
        pi[i][0] = __shfl(m0, i, 8);
        pi[i][1] = __shfl(m1, i, 8);
        pi[i][2] = __shfl(m2, i, 8);
        pi[i][3] = __shfl(m3, i, 8);
        ai[i]    = __shfl(actm, i, 8);
    }
    float pr[6][4];
    #pragma unroll
    for (int i = 0; i < 6; i++)
        quat_pred(&qn[(i*8+j)*4], pi[i][0], pi[i][1], pi[i][2], pi[i][3], pr[i]);
    float c1[6], vx, vy, vz, vw;
    caps_route8<6>(pr, ai, true, c1, vx, vy, vz, vw);
    float acc = 0.f;
    #pragma unroll
    for (int i = 0; i < 6; i++)
        acc += c1[i]*(pr[i][0]*vx + pr[i][1]*vy + pr[i][2]*vz + pr[i][3]*vw);
    actOut[(size_t)v*8 + j] = sigmoidf_(acc);
    *reinterpret_cast<float4*>(&poseOut[((size_t)v*8 + j)*4]) = make_float4(vx, vy, vz, vw);
}

// ---------- pool2 (V=512, N=32768): node-parallel LDS-privatized ----------
template<int V, int J, int CH, int NCHUNK>
__global__ void pool_priv1(const float4* __restrict__ poseIn, const float* __restrict__ actIn,
                           const float* __restrict__ posIn,
                           float* __restrict__ s, float* __restrict__ wsum,
                           float* __restrict__ cnt, float* __restrict__ psum,
                           int N, int G, int mode, const unsigned* __restrict__ mm){
    __shared__ float s_[V*CH*4];
    __shared__ float wsum_[V*CH];
    __shared__ float cnt_[V];
    __shared__ float psum_[V*3];
    const int chunk = blockIdx.x % NCHUNK;
    const int slice = blockIdx.x / NCHUNK;
    const int nslices = gridDim.x / NCHUNK;
    const int c0 = chunk * CH;

    for (int t = threadIdx.x; t < V*CH*4; t += blockDim.x) s_[t] = 0.f;
    for (int t = threadIdx.x; t < V*CH; t += blockDim.x) wsum_[t] = 0.f;
    if (chunk == 0){
        for (int t = threadIdx.x; t < V; t += blockDim.x) cnt_[t] = 0.f;
        for (int t = threadIdx.x; t < V*3; t += blockDim.x) psum_[t] = 0.f;
    }
    __syncthreads();

    float start, size; pool_geom(mm, G, mode, start, size);
    int per = (N + nslices - 1) / nslices;
    int n0 = slice * per, n1 = min(N, n0 + per);

    for (int n = n0 + (int)threadIdx.x; n < n1; n += blockDim.x){
        int vid = voxel_id(posIn, n, G, start, size);
        #pragma unroll
        for (int jj = 0; jj < CH; jj++){
            int j = c0 + jj;
            float aj = actIn[(size_t)n*J + j];
            float4 p = poseIn[(size_t)n*J + j];
            int b = (vid*CH + jj)*4;
            atomicAdd(&s_[b+0], aj*p.x);
            atomicAdd(&s_[b+1], aj*p.y);
            atomicAdd(&s_[b+2], aj*p.z);
            atomicAdd(&s_[b+3], aj*p.w);
            atomicAdd(&wsum_[vid*CH + jj], aj);
        }
        if (chunk == 0){
            atomicAdd(&cnt_[vid], 1.0f);
            atomicAdd(&psum_[vid*3+0], posIn[(size_t)n*3+0]);
            atomicAdd(&psum_[vid*3+1], posIn[(size_t)n*3+1]);
            atomicAdd(&psum_[vid*3+2], posIn[(size_t)n*3+2]);
        }
    }
    __syncthreads();

    for (int t = threadIdx.x; t < V*CH*4; t += blockDim.x){
        float val = s_[t];
        if (val != 0.f){
            int v = t / (CH*4), r = t % (CH*4);
            atomicAdd(&s[((size_t)v*J + c0)*4 + r], val);
        }
    }
    for (int t = threadIdx.x; t < V*CH; t += blockDim.x){
        float val = wsum_[t];
        if (val != 0.f){
            int v = t / CH, jj = t % CH;
            atomicAdd(&wsum[(size_t)v*J + c0 + jj], val);
        }
    }
    if (chunk == 0){
        for (int t = threadIdx.x; t < V; t += blockDim.x)
            if (cnt_[t] != 0.f) atomicAdd(&cnt[t], cnt_[t]);
        for (int t = threadIdx.x; t < V*3; t += blockDim.x)
            if (psum_[t] != 0.f) atomicAdd(&psum[t], psum_[t]);
    }
}

// pool2 agreement pass: m computed INLINE from raw s-sums (normalize expression
// identical to the removed pool_m2 -> bit-identical values, one less launch).
template<int V, int J>
__global__ void pool_priv2n(const float4* __restrict__ poseIn, const float* __restrict__ actIn,
                            const float* __restrict__ posIn, const float4* __restrict__ sraw,
                            float* __restrict__ agacc,
                            int N, int G, int mode, const unsigned* __restrict__ mm){
    __shared__ float ag_[V*J];
    for (int t = threadIdx.x; t < V*J; t += blockDim.x) ag_[t] = 0.f;
    __syncthreads();
    float start, size; pool_geom(mm, G, mode, start, size);
    int nslices = gridDim.x;
    int per = (N + nslices - 1) / nslices;
    int n0 = blockIdx.x * per, n1 = min(N, n0 + per);
    for (int n = n0 + (int)threadIdx.x; n < n1; n += blockDim.x){
        int vid = voxel_id(posIn, n, G, start, size);
        #pragma unroll
        for (int j = 0; j < J; j++){
            float4 p  = poseIn[(size_t)n*J + j];
            float4 sv = sraw[(size_t)vid*J + j];
            float minv = 1.0f/(sqrtf(sv.x*sv.x+sv.y*sv.y+sv.z*sv.z+sv.w*sv.w)+EPS);
            float agree = p.x*(sv.x*minv) + p.y*(sv.y*minv)
                        + p.z*(sv.z*minv) + p.w*(sv.w*minv);
            atomicAdd(&ag_[vid*J + j], actIn[(size_t)n*J + j]*agree);
        }
    }
    __syncthreads();
    for (int t = threadIdx.x; t < V*J; t += blockDim.x)
        if (ag_[t] != 0.f) atomicAdd(&agacc[t], ag_[t]);
}

// ---------- pool3 (V=8, N=512): pos inline from pool2 psum/cnt; dead pos-accum dropped
// (pool4final never reads pos: G=1 forces vid=0 unconditionally) ----------
template<int V, int J, int CH, int NCHUNK>
__global__ void pool_priv1b(const float4* __restrict__ poseIn, const float* __restrict__ actIn,
                            const float* __restrict__ psumIn, const float* __restrict__ cntIn,
                            float* __restrict__ s, float* __restrict__ wsum,
                            int N, int G, int mode, const unsigned* __restrict__ mm){
    __shared__ float s_[V*CH*4];
    __shared__ float wsum_[V*CH];
    const int chunk = blockIdx.x % NCHUNK;
    const int slice = blockIdx.x / NCHUNK;
    const int nslices = gridDim.x / NCHUNK;
    const int c0 = chunk * CH;

    for (int t = threadIdx.x; t < V*CH*4; t += blockDim.x) s_[t] = 0.f;
    for (int t = threadIdx.x; t < V*CH; t += blockDim.x) wsum_[t] = 0.f;
    __syncthreads();

    float start, size; pool_geom(mm, G, mode, start, size);
    int per = (N + nslices - 1) / nslices;
    int n0 = slice * per, n1 = min(N, n0 + per);

    for (int n = n0 + (int)threadIdx.x; n < n1; n += blockDim.x){
        int vid = voxel_id_pc(psumIn, cntIn, n, G, start, size);
        #pragma unroll
        for (int jj = 0; jj < CH; jj++){
            int j = c0 + jj;
            float aj = actIn[(size_t)n*J + j];
            float4 p = poseIn[(size_t)n*J + j];
            int b = (vid*CH + jj)*4;
            atomicAdd(&s_[b+0], aj*p.x);
            atomicAdd(&s_[b+1], aj*p.y);
            atomicAdd(&s_[b+2], aj*p.z);
            atomicAdd(&s_[b+3], aj*p.w);
            atomicAdd(&wsum_[vid*CH + jj], aj);
        }
    }
    __syncthreads();

    for (int t = threadIdx.x; t < V*CH*4; t += blockDim.x){
        float val = s_[t];
        if (val != 0.f){
            int v = t / (CH*4), r = t % (CH*4);
            atomicAdd(&s[((size_t)v*J + c0)*4 + r], val);
        }
    }
    for (int t = threadIdx.x; t < V*CH; t += blockDim.x){
        float val = wsum_[t];
        if (val != 0.f){
            int v = t / CH, jj = t % CH;
            atomicAdd(&wsum[(size_t)v*J + c0 + jj], val);
        }
    }
}

template<int V, int J>
__global__ void pool_priv2b(const float4* __restrict__ poseIn, const float* __restrict__ actIn,
                            const float* __restrict__ psumIn, const float* __restrict__ cntIn,
                            const float4* __restrict__ sraw, float* __restrict__ agacc,
                            int N, int G, int mode, const unsigned* __restrict__ mm){
    __shared__ float ag_[V*J];
    for (int t = threadIdx.x; t < V*J; t += blockDim.x) ag_[t] = 0.f;
    __syncthreads();
    float start, size; pool_geom(mm, G, mode, start, size);
    int nslices = gridDim.x;
    int per = (N + nslices - 1) / nslices;
    int n0 = blockIdx.x * per, n1 = min(N, n0 + per);
    for (int n = n0 + (int)threadIdx.x; n < n1; n += blockDim.x){
        int vid = voxel_id_pc(psumIn, cntIn, n, G, start, size);
        #pragma unroll
        for (int j = 0; j < J; j++){
            float4 p  = poseIn[(size_t)n*J + j];
            float4 sv = sraw[(size_t)vid*J + j];
            float minv = 1.0f/(sqrtf(sv.x*sv.x+sv.y*sv.y+sv.z*sv.z+sv.w*sv.w)+EPS);
            float agree = p.x*(sv.x*minv) + p.y*(sv.y*minv)
                        + p.z*(sv.z*minv) + p.w*(sv.w*minv);
            atomicAdd(&ag_[vid*J + j], actIn[(size_t)n*J + j]*agree);
        }
    }
    __syncthreads();
    for (int t = threadIdx.x; t < V*J; t += blockDim.x)
        if (ag_[t] != 0.f) atomicAdd(&agacc[t], ag_[t]);
}

// ====== cooperative caps: pose = normalize(sraw) computed inline in prologue ======
template<int I, int J, int NPB>
__global__ __launch_bounds__(NPB*I*J)
void caps_coop_fin2(const float* __restrict__ sraw, const float* __restrict__ agacc,
                    const float* __restrict__ wsum, const float* __restrict__ q,
                    float* __restrict__ poseOut, float* __restrict__ actOut, int N){
    const int IJ = I*J;
    const int tid = threadIdx.x;
    const int nl  = tid / IJ;
    const int li  = tid - nl*IJ;
    const int i   = li / J;
    const int j   = li - i*J;
    const int node = blockIdx.x*NPB + nl;
    const bool on = (node < N);

    __shared__ float redA[NPB][I*J];
    __shared__ float redB[NPB][I*J];
    __shared__ float cp[NPB][I*J*4];
    __shared__ float vsh[NPB][J*4];

    float prx=0.f, pry=0.f, prz=0.f, prw=0.f, ai=0.f;
    if (on){
        float qx = q[li*4+0], qy = q[li*4+1], qz = q[li*4+2], qw = q[li*4+3];
        float qinv = 1.0f/(sqrtf(qx*qx+qy*qy+qz*qz+qw*qw)+EPS);
        qx*=qinv; qy*=qinv; qz*=qinv; qw*=qinv;
        const float* sp = &sraw[((size_t)node*I + i)*4];
        float a0=sp[0], a1=sp[1], a2=sp[2], a3=sp[3];
        float minv = 1.0f/(sqrtf(a0*a0+a1*a1+a2*a2+a3*a3)+EPS);
        float rx=a0*minv, ry=a1*minv, rz=a2*minv, rw=a3*minv;
        ai = sigmoidf_(agacc[(size_t)node*I + i] / (wsum[(size_t)node*I + i] + EPS));
        float tx = qw*rx + qx*rw + qy*rz - qz*ry;
        float ty = qw*ry - qx*rz + qy*rw + qz*rx;
        float tz = qw*rz + qx*ry - qy*rx + qz*rw;
        float tw = qw*rw - qx*rx - qy*ry - qz*rz;
        float pinv = 1.0f/(sqrtf(tx*tx+ty*ty+tz*tz+tw*tw)+EPS);
        prx=tx*pinv; pry=ty*pinv; prz=tz*pinv; prw=tw*pinv;
    }

    float b = 0.f, c = 0.f;
    for (int t = 0; t < 3; t++){
        redA[nl][li] = b;
        __syncthreads();
        float mb = -INFINITY;
        #pragma unroll
        for (int jj = 0; jj < J; jj++) mb = fmaxf(mb, redA[nl][i*J+jj]);
        float e = expf(b - mb);
        redB[nl][li] = e;
        __syncthreads();
        float s = 0.f;
        #pragma unroll
        for (int jj = 0; jj < J; jj++) s += redB[nl][i*J+jj];
        c = ai * e / s;
        cp[nl][li*4+0] = c*prx; cp[nl][li*4+1] = c*pry;
        cp[nl][li*4+2] = c*prz; cp[nl][li*4+3] = c*prw;
        __syncthreads();
        for (int idx = li; idx < J*4; idx += IJ){
            int jj = idx >> 2, comp = idx & 3;
            float acc = 0.f;
            #pragma unroll
            for (int ii = 0; ii < I; ii++) acc += cp[nl][(ii*J+jj)*4+comp];
            vsh[nl][idx] = acc;
        }
        __syncthreads();
        if (li < J){
            float a0=vsh[nl][li*4], a1=vsh[nl][li*4+1], a2=vsh[nl][li*4+2], a3=vsh[nl][li*4+3];
            float inv = 1.0f/(sqrtf(a0*a0+a1*a1+a2*a2+a3*a3)+EPS);
            vsh[nl][li*4]=a0*inv; vsh[nl][li*4+1]=a1*inv;
            vsh[nl][li*4+2]=a2*inv; vsh[nl][li*4+3]=a3*inv;
        }
        __syncthreads();
        if (t < 2){
            b += prx*vsh[nl][j*4] + pry*vsh[nl][j*4+1] + prz*vsh[nl][j*4+2] + prw*vsh[nl][j*4+3];
            __syncthreads();
        } else {
            redA[nl][li] = c*(prx*vsh[nl][j*4] + pry*vsh[nl][j*4+1]
                            + prz*vsh[nl][j*4+2] + prw*vsh[nl][j*4+3]);
            __syncthreads();
            if (li < J && on){
                float acc = 0.f;
                #pragma unroll
                for (int ii = 0; ii < I; ii++) acc += redA[nl][ii*J+li];
                actOut[(size_t)node*J + li] = sigmoidf_(acc);
                poseOut[((size_t)node*J+li)*4+0] = vsh[nl][li*4+0];
                poseOut[((size_t)node*J+li)*4+1] = vsh[nl][li*4+1];
                poseOut[((size_t)node*J+li)*4+2] = vsh[nl][li*4+2];
                poseOut[((size_t)node*J+li)*4+3] = vsh[nl][li*4+3];
            }
        }
    }
}

// ====== pool4 (8 nodes -> 1 voxel) + final caps<14,10>, one block ======
__global__ __launch_bounds__(192)
void pool4final_kernel(const float* __restrict__ poseIn, const float* __restrict__ actIn,
                       const float* __restrict__ q7, float* __restrict__ out){
    const int NIN = 8, JP = 14, I = 14, J = 10;
    __shared__ float mp[JP*4], ma[JP];
    __shared__ float redA[I*J], redB[I*J], cp[I*J*4], vsh[J*4];
    int t = threadIdx.x;
    if (t < JP){            // pool4: thread-per-capsule, no atomics
        float s0=0.f,s1=0.f,s2=0.f,s3=0.f,w=0.f;
        #pragma unroll
        for (int n = 0; n < NIN; n++){
            float a = actIn[n*JP + t];
            const float* pb = &poseIn[(n*JP + t)*4];
            s0 += a*pb[0]; s1 += a*pb[1]; s2 += a*pb[2]; s3 += a*pb[3];
            w += a;
        }
        float inv = 1.f/(sqrtf(s0*s0+s1*s1+s2*s2+s3*s3)+EPS);
        s0*=inv; s1*=inv; s2*=inv; s3*=inv;
        float ag = 0.f;
        #pragma unroll
        for (int n = 0; n < NIN; n++){
            float a = actIn[n*JP + t];
            const float* pb = &poseIn[(n*JP + t)*4];
            ag += a*(pb[0]*s0 + pb[1]*s1 + pb[2]*s2 + pb[3]*s3);
        }
        ma[t] = sigmoidf_(ag / (w + EPS));
        mp[t*4+0]=s0; mp[t*4+1]=s1; mp[t*4+2]=s2; mp[t*4+3]=s3;
    }
    __syncthreads();

    bool act_thr = (t < I*J);
    int li = act_thr ? t : 0;
    int i = li / J, j = li % J;
    float prx=0.f, pry=0.f, prz=0.f, prw=0.f, ai=0.f;
    if (act_thr){
        float qx=q7[li*4],qy=q7[li*4+1],qz=q7[li*4+2],qw=q7[li*4+3];
        float qinv = 1.f/(sqrtf(qx*qx+qy*qy+qz*qz+qw*qw)+EPS);
        qx*=qinv; qy*=qinv; qz*=qinv; qw*=qinv;
        float rx=mp[i*4], ry=mp[i*4+1], rz=mp[i*4+2], rw=mp[i*4+3];
        ai = ma[i];
        float tx = qw*rx + qx*rw + qy*rz - qz*ry;
        float ty = qw*ry - qx*rz + qy*rw + qz*rx;
        float tz = qw*rz + qx*ry - qy*rx + qz*rw;
        float tw = qw*rw - qx*rx - qy*ry - qz*rz;
        float pinv = 1.f/(sqrtf(tx*tx+ty*ty+tz*tz+tw*tw)+EPS);
        prx=tx*pinv; pry=ty*pinv; prz=tz*pinv; prw=tw*pinv;
    }
    float b = 0.f, c = 0.f;
    for (int it = 0; it < 3; it++){
        if (act_thr) redA[li] = b;
        __syncthreads();
        float mb = -INFINITY;
        #pragma unroll
        for (int jj = 0; jj < J; jj++) mb = fmaxf(mb, redA[i*J+jj]);
        float e = expf(b - mb);
        if (act_thr) redB[li] = e;
        __syncthreads();
        float s = 0.f;
        #pragma unroll
        for (int jj = 0; jj < J; jj++) s += redB[i*J+jj];
        c = ai * e / s;
        if (act_thr){
            cp[li*4+0]=c*prx; cp[li*4+1]=c*pry; cp[li*4+2]=c*prz; cp[li*4+3]=c*prw;
        }
        __syncthreads();
        if (act_thr){
            for (int idx = li; idx < J*4; idx += I*J){
                int jj = idx >> 2, comp = idx & 3;
                float acc = 0.f;
                #pragma unroll
                for (int ii = 0; ii < I; ii++) acc += cp[(ii*J+jj)*4+comp];
                vsh[idx] = acc;
            }
        }
        __syncthreads();
        if (act_thr && li < J){
            float a0=vsh[li*4], a1=vsh[li*4+1], a2=vsh[li*4+2], a3=vsh[li*4+3];
            float inv = 1.f/(sqrtf(a0*a0+a1*a1+a2*a2+a3*a3)+EPS);
            vsh[li*4]=a0*inv; vsh[li*4+1]=a1*inv; vsh[li*4+2]=a2*inv; vsh[li*4+3]=a3*inv;
        }
        __syncthreads();
        if (it < 2){
            b += prx*vsh[j*4] + pry*vsh[j*4+1] + prz*vsh[j*4+2] + prw*vsh[j*4+3];
            __syncthreads();
        } else {
            if (act_thr)
                redA[li] = c*(prx*vsh[j*4] + pry*vsh[j*4+1]
                            + prz*vsh[j*4+2] + prw*vsh[j*4+3]);
            __syncthreads();
            if (act_thr && li < J){
                float acc = 0.f;
                #pragma unroll
                for (int ii = 0; ii < I; ii++) acc += redA[ii*J+li];
                out[li] = sigmoidf_(acc);
            }
        }
    }
}

extern "C" void kernel_launch(void* const* d_in, const int* in_sizes, int n_in,
                              void* d_out, int out_size, void* d_ws, size_t ws_size,
                              hipStream_t stream){
    const float* x      = (const float*)d_in[0];
    const float* pos    = (const float*)d_in[1];
    const float* pseudo = (const float*)d_in[2];
    const float* Wsp    = (const float*)d_in[3];
    const float* root   = (const float*)d_in[4];
    const float* bias   = (const float*)d_in[5];
    const float* lin_w  = (const float*)d_in[6];
    const float* lin_b  = (const float*)d_in[7];
    const float* q0     = (const float*)d_in[8];
    const float* q1     = (const float*)d_in[9];
    const float* q3     = (const float*)d_in[10];
    const float* q5     = (const float*)d_in[11];
    const float* q6     = (const float*)d_in[12];
    const float* q7     = (const float*)d_in[13];
    const int*   ei     = (const int*)d_in[14];
    const int N = in_sizes[0];
    const int E = in_sizes[2] / 3;
    const int V1 = 32768;
    const int NB = (N + 255)/256;

    char* ws = (char*)d_ws;
    size_t off = 0;
    auto alloc = [&](size_t bytes)->void*{
        void* p = ws + off;
        off += (bytes + 255) & ~(size_t)255;
        return p;
    };
    unsigned* mm   = (unsigned*)alloc(8);
    int* deg       = (int*)alloc((size_t)N*sizeof(int));
    int* erank     = (int*)alloc((size_t)E*sizeof(int));
    int* eoff      = (int*)alloc((size_t)(N+1)*sizeof(int));
    int* bsum      = (int*)alloc((size_t)(NB+1)*sizeof(int));
    float4* rec4   = (float4*)alloc((size_t)E*sizeof(float4));
    int* recb      = (int*)alloc((size_t)E*sizeof(int));
    int* vhead     = (int*)alloc((size_t)V1*sizeof(int));
    int* vnxt      = (int*)alloc((size_t)N*sizeof(int));
    float* P0  = (float*)alloc((size_t)1250000*sizeof(float));
    float* P1  = (float*)alloc((size_t)1250000*sizeof(float));
    float* A0  = (float*)alloc((size_t)310000*sizeof(float));
    float* A1  = (float*)alloc((size_t)310000*sizeof(float));
    float* PB0 = (float*)alloc((size_t)100000*sizeof(float));
    float* PB1 = (float*)alloc((size_t)100000*sizeof(float));
    size_t z0 = off;                                // zeroed pool-scratch region start
    float* vs2 = (float*)alloc((size_t)512*8*4*sizeof(float));
    float* vw2 = (float*)alloc((size_t)512*8*sizeof(float));
    float* va2 = (float*)alloc((size_t)512*8*sizeof(float));
    float* vc2 = (float*)alloc((size_t)512*sizeof(float));
    float* vp2 = (float*)alloc((size_t)512*3*sizeof(float));
    float* vs3 = (float*)alloc((size_t)8*12*4*sizeof(float));
    float* vw3 = (float*)alloc((size_t)8*12*sizeof(float));
    float* va3 = (float*)alloc((size_t)8*12*sizeof(float));
    size_t z1 = off;
    float* pzero = (float*)(ws + z0);
    const int PZ = (int)((z1 - z0)/sizeof(float));  // zero whole region incl. padding

    // 15 dispatches (pool_m2 x2 removed: normalize/pos-divide inlined bit-identically;
    // pool3's pos outputs were dead -- pool4 has G=1 => vid=0 unconditionally).
    init_kernel<<<256, 256, 0, stream>>>(mm, deg, N, vhead, V1, pzero, PZ);
    prep_kernel<<<512, 256, 0, stream>>>(pos, N*3, mm, ei, deg, erank, E);
    scan_bsum<<<NB, 256, 0, stream>>>(deg, bsum, N);
    scan_final2<<<NB, 256, 0, stream>>>(deg, bsum, eoff, N, NB);
    edge_pack<<<(E + 255)/256, 256, 0, stream>>>(ei, pseudo, x, erank, eoff, rec4, recb, E);
    spline_node_kernel<<<(8*N + 255)/256, 256, 0, stream>>>(x, rec4, recb, eoff, Wsp,
                                                            root, bias, lin_w, lin_b, P0, A0, N);

    // caps<1,6> + caps<6,6> + pool1 list build, fused
    caps01_kernel<<<(8*N + 255)/256, 256, 0, stream>>>(P0, A0, q0, q1, P1, A1,
                                                       pos, vhead, vnxt, N, 32, mm);
    // pool1 gather + caps<6,8>, fused
    pool1caps_kernel<<<(8*V1 + 255)/256, 256, 0, stream>>>(P1, A1, pos, vhead, vnxt,
                                                           q3, P0, A0, PB0, V1);

    // pool2: 32768 -> 512 (G=8), J=8
    pool_priv1<512,8,4,2><<<128, 256, 0, stream>>>((const float4*)P0, A0, PB0,
                                                   vs2, vw2, vc2, vp2, 32768, 8, 0, mm);
    pool_priv2n<512,8><<<64, 256, 0, stream>>>((const float4*)P0, A0, PB0,
                                               (const float4*)vs2, va2, 32768, 8, 0, mm);
    caps_coop_fin2<8,12,2><<<256, 2*96, 0, stream>>>(vs2, va2, vw2, q5, P0, A0, 512);

    // pool3: 512 -> 8 (G=2), J=12 — pos from pool2 psum/cnt inline; no dead pos work
    pool_priv1b<8,12,12,1><<<16, 256, 0, stream>>>((const float4*)P0, A0, vp2, vc2,
                                                   vs3, vw3, 512, 2, 0, mm);
    pool_priv2b<8,12><<<16, 256, 0, stream>>>((const float4*)P0, A0, vp2, vc2,
                                              (const float4*)vs3, va3, 512, 2, 0, mm);
    caps_coop_fin2<12,14,1><<<8, 168, 0, stream>>>(vs3, va3, vw3, q6, P0, A0, 8);

    // pool4 + final caps<14,10>, fused single block -> d_out
    pool4final_kernel<<<1, 192, 0, stream>>>(P0, A0, q7, (float*)d_out);
}